// Round 10
// baseline (438.946 us; speedup 1.0000x reference)
//
#include <hip/hip_runtime.h>

typedef unsigned short u16;
typedef u16 u16x4 __attribute__((ext_vector_type(4)));
typedef short short8 __attribute__((ext_vector_type(8)));
typedef float f32x4 __attribute__((ext_vector_type(4)));

__device__ __forceinline__ float elu_f(float x) { return x > 0.f ? x : expm1f(x); }
__device__ __forceinline__ float lrelu_f(float x) { return x > 0.f ? x : 0.2f * x; }

__device__ __forceinline__ u16 f2b(float f) {
  union { float f; unsigned u; } v; v.f = f;
  unsigned r = v.u + 0x7FFF + ((v.u >> 16) & 1);
  return (u16)(r >> 16);
}
__device__ __forceinline__ float b2f(u16 u) {
  union { unsigned u; float f; } v; v.u = ((unsigned)u) << 16; return v.f;
}

// ---------------- fused conversions + degree count ----------------
__global__ __launch_bounds__(256) void cvtdeg_k(const float* __restrict__ x, u16* __restrict__ xb,
                                                int nx8,
                                                const float* __restrict__ pw,
                                                const float* __restrict__ w0,
                                                const float* __restrict__ w1,
                                                const float* __restrict__ w2,
                                                u16* __restrict__ dp, u16* __restrict__ d0,
                                                u16* __restrict__ d1, u16* __restrict__ d2,
                                                const int* __restrict__ edst,
                                                int E, int n, int* __restrict__ deg) {
  int i = blockIdx.x * 256 + threadIdx.x;
  if (i < nx8) {
    int j = i * 8;
    float4 a = *reinterpret_cast<const float4*>(&x[j]);
    float4 b = *reinterpret_cast<const float4*>(&x[j + 4]);
    u16x4 o0, o1;
    o0.x = f2b(a.x); o0.y = f2b(a.y); o0.z = f2b(a.z); o0.w = f2b(a.w);
    o1.x = f2b(b.x); o1.y = f2b(b.y); o1.z = f2b(b.z); o1.w = f2b(b.w);
    *reinterpret_cast<u16x4*>(&xb[j]) = o0;
    *reinterpret_cast<u16x4*>(&xb[j + 4]) = o1;
  } else if (i < nx8 + 155648) {
    int j = i - nx8;
    if (j < 8192) dp[j] = f2b(pw[j]);
    else if (j < 24576) d0[j - 8192] = f2b(w0[j - 8192]);
    else if (j < 90112) d1[j - 24576] = f2b(w1[j - 24576]);
    else d2[j - 90112] = f2b(w2[j - 90112]);
  } else {
    int j = i - (nx8 + 155648);
    if (j < E) atomicAdd(&deg[edst[j]], 1);
    else if (j < E + n) atomicAdd(&deg[j - E], 1);  // self loop
  }
}

__global__ __launch_bounds__(256) void block_sum_k(const int* __restrict__ deg,
                                                   int* __restrict__ bsum, int n) {
  int i = blockIdx.x * 256 + threadIdx.x;
  int v = (i < n) ? deg[i] : 0;
#pragma unroll
  for (int off = 1; off < 64; off <<= 1) v += __shfl_xor(v, off);
  __shared__ int ws[4];
  if ((threadIdx.x & 63) == 0) ws[threadIdx.x >> 6] = v;
  __syncthreads();
  if (threadIdx.x == 0) bsum[blockIdx.x] = ws[0] + ws[1] + ws[2] + ws[3];
}

__global__ void scan_bsum_k(int* __restrict__ bsum, int nb) {
  __shared__ int s[1024];
  int tid = threadIdx.x;
  int v = (tid < nb) ? bsum[tid] : 0;
  s[tid] = v;
  __syncthreads();
  for (int off = 1; off < 1024; off <<= 1) {
    int t = (tid >= off) ? s[tid - off] : 0;
    __syncthreads();
    s[tid] += t;
    __syncthreads();
  }
  if (tid < nb) bsum[tid] = s[tid] - v;  // exclusive
}

__global__ __launch_bounds__(256) void block_scan_k(const int* __restrict__ deg,
                                                    const int* __restrict__ bsum,
                                                    int* __restrict__ rowptr,
                                                    int* __restrict__ cursor, int n) {
  int i = blockIdx.x * 256 + threadIdx.x;
  int lane = threadIdx.x & 63, w = threadIdx.x >> 6;
  int v = (i < n) ? deg[i] : 0;
  int x = v;
#pragma unroll
  for (int off = 1; off < 64; off <<= 1) {
    int t = __shfl_up(x, off);
    if (lane >= off) x += t;
  }
  __shared__ int ws[4];
  if (lane == 63) ws[w] = x;
  __syncthreads();
  int add = bsum[blockIdx.x];
  for (int j = 0; j < w; ++j) add += ws[j];
  int excl = x - v + add;
  if (i < n) {
    cursor[i] = excl;
    rowptr[i + 1] = excl + v;
  }
  if (i == 0) rowptr[0] = 0;
}

__global__ void scatter_k(const int* __restrict__ src, const int* __restrict__ dst,
                          int E, int n, int* __restrict__ cursor,
                          int* __restrict__ col, int* __restrict__ dst2) {
  int e = blockIdx.x * blockDim.x + threadIdx.x;
  if (e < E) {
    int d = dst[e];
    int pos = atomicAdd(&cursor[d], 1);
    col[pos] = src[e];
    dst2[pos] = d;
  } else if (e < E + n) {
    int d = e - E;
    int pos = atomicAdd(&cursor[d], 1);
    col[pos] = d;  // self loop
    dst2[pos] = d;
  }
}

// ---------------- bf16 MFMA GEMM, 128x256 tile, fused attn scores (+optional fused proj) ----------------
template <int PROJ>
__global__ __launch_bounds__(512) void gemm2_k(const u16* __restrict__ A, int lda,
                                               const u16* __restrict__ W,
                                               const u16* __restrict__ pw,
                                               const float* __restrict__ pb,
                                               u16* __restrict__ Cb,
                                               int n, int K,
                                               const float* __restrict__ a_sv,
                                               const float* __restrict__ a_dv,
                                               float* __restrict__ asrcN,
                                               float* __restrict__ adstN) {
  __shared__ char Asb[128 * 128];  // 128 rows x 128B, XOR-swizzled
  __shared__ char Bsb[256 * 128];  // 256 rows x 128B
  __shared__ char Xsb[PROJ ? 128 * 272 : 16];
  __shared__ char Psb[PROJ ? 64 * 272 : 16];
  const int t = threadIdx.x;
  const int lane = t & 63, w = t >> 6;
  const int wrow = w >> 2, wcol = w & 3;
  const int row0 = blockIdx.x * 128;

  if (PROJ) {
#pragma unroll
    for (int i = 0; i < 4; ++i) {  // xb tile: 128 rows x 256B
      int ci = i * 512 + t;
      int r = ci >> 4;
      int b = (ci & 15) << 4;
      int ar = row0 + r; ar = ar < n ? ar : n - 1;
      *reinterpret_cast<int4*>(Xsb + r * 272 + b) =
          *reinterpret_cast<const int4*>(&A[(size_t)ar * 128 + (b >> 1)]);
    }
#pragma unroll
    for (int i = 0; i < 2; ++i) {  // pw: 64 rows x 256B
      int ci = i * 512 + t;
      int r = ci >> 4;
      int b = (ci & 15) << 4;
      *reinterpret_cast<int4*>(Psb + r * 272 + b) =
          *reinterpret_cast<const int4*>(&pw[r * 128 + (b >> 1)]);
    }
    __syncthreads();
    f32x4 pacc[4];
#pragma unroll
    for (int nf = 0; nf < 4; ++nf) pacc[nf] = (f32x4){0.f, 0.f, 0.f, 0.f};
#pragma unroll
    for (int ks = 0; ks < 4; ++ks) {  // K=128
      short8 paf = *reinterpret_cast<const short8*>(
          Xsb + (w * 16 + (lane & 15)) * 272 + ks * 64 + (lane >> 4) * 16);
#pragma unroll
      for (int nf = 0; nf < 4; ++nf) {
        short8 pbf = *reinterpret_cast<const short8*>(
            Psb + (nf * 16 + (lane & 15)) * 272 + ks * 64 + (lane >> 4) * 16);
        pacc[nf] = __builtin_amdgcn_mfma_f32_16x16x32_bf16(paf, pbf, pacc[nf], 0, 0, 0);
      }
    }
#pragma unroll
    for (int nf = 0; nf < 4; ++nf) {
#pragma unroll
      for (int j = 0; j < 4; ++j) {
        int rl = w * 16 + (lane >> 4) * 4 + j;
        int cg = nf * 16 + (lane & 15);
        u16 bv = f2b(elu_f(pacc[nf][j] + pb[cg]));
        *reinterpret_cast<u16*>(Asb + rl * 128 + ((cg * 2) ^ ((rl & 7) << 4))) = bv;
      }
    }
  }

  f32x4 acc[4][4];
#pragma unroll
  for (int m = 0; m < 4; ++m)
#pragma unroll
    for (int nf = 0; nf < 4; ++nf) acc[m][nf] = (f32x4){0.f, 0.f, 0.f, 0.f};

  for (int k0 = 0; k0 < K; k0 += 64) {
    if (!PROJ) {
#pragma unroll
      for (int i = 0; i < 2; ++i) {
        int ci = i * 512 + t;
        int r = ci >> 3;
        int b = (ci & 7) << 4;
        int sw = b ^ ((r & 7) << 4);
        int ar = row0 + r; ar = ar < n ? ar : n - 1;
        int4 av = *reinterpret_cast<const int4*>(&A[(size_t)ar * lda + k0 + (b >> 1)]);
        *reinterpret_cast<int4*>(Asb + r * 128 + sw) = av;
      }
    }
#pragma unroll
    for (int i = 0; i < 4; ++i) {
      int ci = i * 512 + t;
      int r = ci >> 3;
      int b = (ci & 7) << 4;
      int sw = b ^ ((r & 7) << 4);
      int4 wv = *reinterpret_cast<const int4*>(&W[(size_t)r * K + k0 + (b >> 1)]);
      *reinterpret_cast<int4*>(Bsb + r * 128 + sw) = wv;
    }
    __syncthreads();
#pragma unroll
    for (int ks = 0; ks < 2; ++ks) {
      short8 af[4], bf[4];
      int kb = ks * 64 + ((lane >> 4) << 4);
#pragma unroll
      for (int m = 0; m < 4; ++m) {
        int r = wrow * 64 + m * 16 + (lane & 15);
        af[m] = *reinterpret_cast<const short8*>(Asb + r * 128 + (kb ^ ((r & 7) << 4)));
      }
#pragma unroll
      for (int nf = 0; nf < 4; ++nf) {
        int r = wcol * 64 + nf * 16 + (lane & 15);
        bf[nf] = *reinterpret_cast<const short8*>(Bsb + r * 128 + (kb ^ ((r & 7) << 4)));
      }
#pragma unroll
      for (int m = 0; m < 4; ++m)
#pragma unroll
        for (int nf = 0; nf < 4; ++nf)
          acc[m][nf] = __builtin_amdgcn_mfma_f32_16x16x32_bf16(af[m], bf[nf], acc[m][nf], 0, 0, 0);
    }
    __syncthreads();
  }
#pragma unroll
  for (int m = 0; m < 4; ++m) {
#pragma unroll
    for (int j = 0; j < 4; ++j) {
      int rg = row0 + wrow * 64 + m * 16 + (lane >> 4) * 4 + j;
      if (rg >= n) continue;
#pragma unroll
      for (int nf = 0; nf < 4; ++nf) {
        int cg = wcol * 64 + nf * 16 + (lane & 15);
        Cb[(size_t)rg * 256 + cg] = f2b(acc[m][nf][j]);
      }
    }
  }
  {
    int h = wcol;
    int ch = lane & 15;
    float as_c[4], ad_c[4];
#pragma unroll
    for (int nf = 0; nf < 4; ++nf) {
      as_c[nf] = a_sv[h * 64 + nf * 16 + ch];
      ad_c[nf] = a_dv[h * 64 + nf * 16 + ch];
    }
#pragma unroll
    for (int m = 0; m < 4; ++m) {
#pragma unroll
      for (int j = 0; j < 4; ++j) {
        float ps = 0.f, pd = 0.f;
#pragma unroll
        for (int nf = 0; nf < 4; ++nf) {
          float v = acc[m][nf][j];
          ps += v * as_c[nf];
          pd += v * ad_c[nf];
        }
#pragma unroll
        for (int off = 1; off < 16; off <<= 1) {
          ps += __shfl_xor(ps, off);
          pd += __shfl_xor(pd, off);
        }
        int rg = row0 + wrow * 64 + m * 16 + (lane >> 4) * 4 + j;
        if ((lane & 15) == 0 && rg < n) {
          asrcN[(size_t)rg * 4 + h] = ps;
          adstN[(size_t)rg * 4 + h] = pd;
        }
      }
    }
  }
}

// ---------------- edge-parallel softmax numerators, transposed: exT[h][e] ----------------
__global__ __launch_bounds__(256) void edge_ex2_k(const int* __restrict__ col,
                                                  const int* __restrict__ dst2,
                                                  const float* __restrict__ asrcN,
                                                  const float* __restrict__ adstN,
                                                  float* __restrict__ exT, int eep, int EE) {
  int e = blockIdx.x * 256 + threadIdx.x;
  if (e >= EE) return;
  int s = col[e], d = dst2[e];
  float4 as = *reinterpret_cast<const float4*>(&asrcN[(size_t)s * 4]);
  float4 ad = *reinterpret_cast<const float4*>(&adstN[(size_t)d * 4]);
  exT[e]            = __expf(lrelu_f(as.x + ad.x));  // softmax shift-invariant; |a| <~ 5
  exT[eep + e]      = __expf(lrelu_f(as.y + ad.y));
  exT[2 * eep + e]  = __expf(lrelu_f(as.z + ad.z));
  exT[3 * eep + e]  = __expf(lrelu_f(as.w + ad.w));
}

// ---------------- persistent-wave GAT aggregation + bias + LayerNorm + ELU ----------------
// grid = 2048 blocks (full residency); each wave strides over nodes.
// MODE 0: LN(256) -> bf16 row at (u16*)out + node*256
// MODE 1: head-mean -> bias -> LN(64) -> ELU -> f32 out[node*64..]
template <int MODE>
__global__ __launch_bounds__(256) void gat_agg5_k(const u16* __restrict__ feat,
                                                  const float* __restrict__ exT, int eep,
                                                  const int* __restrict__ rowptr,
                                                  const int* __restrict__ col,
                                                  const float* __restrict__ bias,
                                                  const float* __restrict__ g,
                                                  const float* __restrict__ be,
                                                  void* __restrict__ out, int n, int nwaves) {
  int wave = threadIdx.x >> 6, lane = threadIdx.x & 63;
  int wid = blockIdx.x * 4 + wave;
  int h = lane >> 4;
  const float* exh = exT + (size_t)h * eep;
  for (int node = wid; node < n; node += nwaves) {
    int s0 = rowptr[node], s1 = rowptr[node + 1];
    float ax = 0.f, ay = 0.f, az = 0.f, aw = 0.f, den = 0.f;
    int e = s0;
    for (; e + 8 <= s1; e += 8) {
      int p0 = col[e + 0], p1 = col[e + 1], p2 = col[e + 2], p3 = col[e + 3];
      int q0 = col[e + 4], q1 = col[e + 5], q2 = col[e + 6], q3 = col[e + 7];
      float u0 = exh[e + 0], u1 = exh[e + 1], u2 = exh[e + 2], u3 = exh[e + 3];
      float v0 = exh[e + 4], v1 = exh[e + 5], v2 = exh[e + 6], v3 = exh[e + 7];
      u16x4 fp0 = *reinterpret_cast<const u16x4*>(&feat[(size_t)p0 * 256 + lane * 4]);
      u16x4 fp1 = *reinterpret_cast<const u16x4*>(&feat[(size_t)p1 * 256 + lane * 4]);
      u16x4 fp2 = *reinterpret_cast<const u16x4*>(&feat[(size_t)p2 * 256 + lane * 4]);
      u16x4 fp3 = *reinterpret_cast<const u16x4*>(&feat[(size_t)p3 * 256 + lane * 4]);
      u16x4 fq0 = *reinterpret_cast<const u16x4*>(&feat[(size_t)q0 * 256 + lane * 4]);
      u16x4 fq1 = *reinterpret_cast<const u16x4*>(&feat[(size_t)q1 * 256 + lane * 4]);
      u16x4 fq2 = *reinterpret_cast<const u16x4*>(&feat[(size_t)q2 * 256 + lane * 4]);
      u16x4 fq3 = *reinterpret_cast<const u16x4*>(&feat[(size_t)q3 * 256 + lane * 4]);
      den += ((u0 + u1) + (u2 + u3)) + ((v0 + v1) + (v2 + v3));
      ax += u0 * b2f(fp0.x) + u1 * b2f(fp1.x) + u2 * b2f(fp2.x) + u3 * b2f(fp3.x);
      ay += u0 * b2f(fp0.y) + u1 * b2f(fp1.y) + u2 * b2f(fp2.y) + u3 * b2f(fp3.y);
      az += u0 * b2f(fp0.z) + u1 * b2f(fp1.z) + u2 * b2f(fp2.z) + u3 * b2f(fp3.z);
      aw += u0 * b2f(fp0.w) + u1 * b2f(fp1.w) + u2 * b2f(fp2.w) + u3 * b2f(fp3.w);
      ax += v0 * b2f(fq0.x) + v1 * b2f(fq1.x) + v2 * b2f(fq2.x) + v3 * b2f(fq3.x);
      ay += v0 * b2f(fq0.y) + v1 * b2f(fq1.y) + v2 * b2f(fq2.y) + v3 * b2f(fq3.y);
      az += v0 * b2f(fq0.z) + v1 * b2f(fq1.z) + v2 * b2f(fq2.z) + v3 * b2f(fq3.z);
      aw += v0 * b2f(fq0.w) + v1 * b2f(fq1.w) + v2 * b2f(fq2.w) + v3 * b2f(fq3.w);
    }
    for (; e + 4 <= s1; e += 4) {
      int p0 = col[e + 0], p1 = col[e + 1], p2 = col[e + 2], p3 = col[e + 3];
      float u0 = exh[e + 0], u1 = exh[e + 1], u2 = exh[e + 2], u3 = exh[e + 3];
      u16x4 fp0 = *reinterpret_cast<const u16x4*>(&feat[(size_t)p0 * 256 + lane * 4]);
      u16x4 fp1 = *reinterpret_cast<const u16x4*>(&feat[(size_t)p1 * 256 + lane * 4]);
      u16x4 fp2 = *reinterpret_cast<const u16x4*>(&feat[(size_t)p2 * 256 + lane * 4]);
      u16x4 fp3 = *reinterpret_cast<const u16x4*>(&feat[(size_t)p3 * 256 + lane * 4]);
      den += (u0 + u1) + (u2 + u3);
      ax += u0 * b2f(fp0.x) + u1 * b2f(fp1.x) + u2 * b2f(fp2.x) + u3 * b2f(fp3.x);
      ay += u0 * b2f(fp0.y) + u1 * b2f(fp1.y) + u2 * b2f(fp2.y) + u3 * b2f(fp3.y);
      az += u0 * b2f(fp0.z) + u1 * b2f(fp1.z) + u2 * b2f(fp2.z) + u3 * b2f(fp3.z);
      aw += u0 * b2f(fp0.w) + u1 * b2f(fp1.w) + u2 * b2f(fp2.w) + u3 * b2f(fp3.w);
    }
    for (; e < s1; ++e) {
      int s = col[e];
      float xv = exh[e];
      den += xv;
      u16x4 f = *reinterpret_cast<const u16x4*>(&feat[(size_t)s * 256 + lane * 4]);
      ax += xv * b2f(f.x); ay += xv * b2f(f.y); az += xv * b2f(f.z); aw += xv * b2f(f.w);
    }
    float inv = 1.f / den;  // self-loop guarantees den > 0
    ax *= inv; ay *= inv; az *= inv; aw *= inv;

    if (MODE == 0) {
      float4 b4 = *reinterpret_cast<const float4*>(&bias[lane * 4]);
      float vx = ax + b4.x, vy = ay + b4.y, vz = az + b4.z, vw = aw + b4.w;
      float s = vx + vy + vz + vw;
#pragma unroll
      for (int off = 1; off < 64; off <<= 1) s += __shfl_xor(s, off);
      float mu = s * (1.f / 256.f);
      float dx = vx - mu, dy = vy - mu, dz = vz - mu, dw = vw - mu;
      float q = dx * dx + dy * dy + dz * dz + dw * dw;
#pragma unroll
      for (int off = 1; off < 64; off <<= 1) q += __shfl_xor(q, off);
      float inv2 = rsqrtf(q * (1.f / 256.f) + 1e-5f);
      float4 gg = *reinterpret_cast<const float4*>(&g[lane * 4]);
      float4 bb = *reinterpret_cast<const float4*>(&be[lane * 4]);
      u16x4 o;
      o.x = f2b(elu_f(dx * inv2 * gg.x + bb.x));
      o.y = f2b(elu_f(dy * inv2 * gg.y + bb.y));
      o.z = f2b(elu_f(dz * inv2 * gg.z + bb.z));
      o.w = f2b(elu_f(dw * inv2 * gg.w + bb.w));
      u16* rowb = (u16*)out + (size_t)node * 256;
      *reinterpret_cast<u16x4*>(&rowb[lane * 4]) = o;
    } else {
      ax += __shfl_xor(ax, 16); ax += __shfl_xor(ax, 32);
      ay += __shfl_xor(ay, 16); ay += __shfl_xor(ay, 32);
      az += __shfl_xor(az, 16); az += __shfl_xor(az, 32);
      aw += __shfl_xor(aw, 16); aw += __shfl_xor(aw, 32);
      int qd = lane & 15;
      float4 b4 = *reinterpret_cast<const float4*>(&bias[qd * 4]);
      float vx = 0.25f * ax + b4.x, vy = 0.25f * ay + b4.y;
      float vz = 0.25f * az + b4.z, vw = 0.25f * aw + b4.w;
      float s = vx + vy + vz + vw;
#pragma unroll
      for (int off = 1; off < 64; off <<= 1) s += __shfl_xor(s, off);
      float mu = s * (1.f / 256.f);
      float dx = vx - mu, dy = vy - mu, dz = vz - mu, dw = vw - mu;
      float q = dx * dx + dy * dy + dz * dz + dw * dw;
#pragma unroll
      for (int off = 1; off < 64; off <<= 1) q += __shfl_xor(q, off);
      float inv2 = rsqrtf(q * (1.f / 256.f) + 1e-5f);
      if (lane < 16) {
        float4 gg = *reinterpret_cast<const float4*>(&g[qd * 4]);
        float4 bb = *reinterpret_cast<const float4*>(&be[qd * 4]);
        float4 o;
        o.x = elu_f(dx * inv2 * gg.x + bb.x);
        o.y = elu_f(dy * inv2 * gg.y + bb.y);
        o.z = elu_f(dz * inv2 * gg.z + bb.z);
        o.w = elu_f(dw * inv2 * gg.w + bb.w);
        *reinterpret_cast<float4*>(&((float*)out)[(size_t)node * 64 + qd * 4]) = o;
      }
    }
  }
}

// ---------------- value head: out[n,4] ----------------
__global__ __launch_bounds__(256) void value_head_k(const float* __restrict__ hh,
                                                    const float* __restrict__ vw1,
                                                    const float* __restrict__ vb1,
                                                    const float* __restrict__ vw2,
                                                    const float* __restrict__ vb2,
                                                    float* __restrict__ out, int n) {
  __shared__ float w1s[32 * 65];
  __shared__ float hs[4][64];
  __shared__ float vs[4][33];
  int tid = threadIdx.x;
  for (int i = tid; i < 2048; i += 256) w1s[(i >> 6) * 65 + (i & 63)] = vw1[i];
  int wave = tid >> 6, lane = tid & 63;
  int node = blockIdx.x * 4 + wave;
  int nc = node < n ? node : n - 1;
  hs[wave][lane] = hh[(size_t)nc * 64 + lane];
  __syncthreads();
  int j = lane & 31, half = lane >> 5;
  float p = 0.f;
#pragma unroll
  for (int c = 0; c < 32; ++c) p += hs[wave][half * 32 + c] * w1s[j * 65 + half * 32 + c];
  p += __shfl_xor(p, 32);
  float v = elu_f(p + vb1[j]);
  if (half == 0) vs[wave][j] = v;
  __syncthreads();
  if (lane < 4 && node < n) {
    float o = vb2[lane];
#pragma unroll
    for (int jj = 0; jj < 32; ++jj) o += vs[wave][jj] * vw2[lane * 32 + jj];
    out[(size_t)node * 4 + lane] = o;
  }
}

extern "C" void kernel_launch(void* const* d_in, const int* in_sizes, int n_in,
                              void* d_out, int out_size, void* d_ws, size_t ws_size,
                              hipStream_t stream) {
  const float* x      = (const float*)d_in[0];
  const int*   esrc   = (const int*)d_in[1];
  const int*   edst   = (const int*)d_in[2];
  const float* proj_w = (const float*)d_in[3];
  const float* proj_b = (const float*)d_in[4];
  const float* w[3]   = {(const float*)d_in[5],  (const float*)d_in[11], (const float*)d_in[17]};
  const float* a_s[3] = {(const float*)d_in[6],  (const float*)d_in[12], (const float*)d_in[18]};
  const float* a_d[3] = {(const float*)d_in[7],  (const float*)d_in[13], (const float*)d_in[19]};
  const float* bb[3]  = {(const float*)d_in[8],  (const float*)d_in[14], (const float*)d_in[20]};
  const float* gg[3]  = {(const float*)d_in[9],  (const float*)d_in[15], (const float*)d_in[21]};
  const float* be[3]  = {(const float*)d_in[10], (const float*)d_in[16], (const float*)d_in[22]};
  const float* vw1 = (const float*)d_in[23];
  const float* vb1 = (const float*)d_in[24];
  const float* vw2 = (const float*)d_in[25];
  const float* vb2 = (const float*)d_in[26];
  float* outp = (float*)d_out;

  const int n = in_sizes[0] / 128;
  const int E = in_sizes[1];
  const int EE = E + n;
  const int eep = (EE + 255) & ~255;
  const int nbl = (n + 255) / 256;

  // ---- workspace layout ----
  char* p = (char*)d_ws;
  auto alloc = [&](size_t bytes) { char* r = p; p += (bytes + 255) & ~(size_t)255; return r; };
  u16*   hA    = (u16*)alloc((size_t)n * 512);     // packed bf16 [n,256]; hfinal f32 [n,64] later
  u16*   featB = (u16*)alloc((size_t)n * 512);     // bf16 [n,256] gemm output
  u16*   xb    = (u16*)alloc((size_t)n * 256);     // bf16 [n,128] input x (own buffer)
  float* exT   = (float*)alloc((size_t)eep * 16);  // transposed numerators [4][eep]
  float* asrcN = (float*)alloc((size_t)n * 16);
  float* adstN = (float*)alloc((size_t)n * 16);
  u16* wbp = (u16*)alloc(64 * 128 * 2);
  u16* wb[3];
  wb[0] = (u16*)alloc(256 * 64 * 2);
  wb[1] = (u16*)alloc(256 * 256 * 2);
  wb[2] = (u16*)alloc(256 * 256 * 2);
  int* deg    = (int*)alloc((size_t)n * 4);
  int* rowptr = (int*)alloc((size_t)(n + 1) * 4);
  int* cursor = (int*)alloc((size_t)n * 4);
  int* col    = (int*)alloc((size_t)EE * 4);
  int* dst2   = (int*)alloc((size_t)EE * 4);
  int* bsum   = (int*)alloc((size_t)nbl * 4);
  float* hfinal = (float*)hA;  // f32 [n,64]; hA dead after layer-2 gemm reads it

  // ---- CSR build + conversions ----
  hipMemsetAsync(deg, 0, (size_t)n * sizeof(int), stream);
  const int nx8 = n * 16;
  cvtdeg_k<<<(nx8 + 155648 + EE + 255) / 256, 256, 0, stream>>>(
      x, xb, nx8, proj_w, w[0], w[1], w[2], wbp, wb[0], wb[1], wb[2], edst, E, n, deg);
  block_sum_k<<<nbl, 256, 0, stream>>>(deg, bsum, n);
  scan_bsum_k<<<1, 1024, 0, stream>>>(bsum, nbl);
  block_scan_k<<<nbl, 256, 0, stream>>>(deg, bsum, rowptr, cursor, n);
  scatter_k<<<(EE + 255) / 256, 256, 0, stream>>>(esrc, edst, E, n, cursor, col, dst2);

  const int nb4 = (n + 3) / 4;
  const int nbg = (n + 127) / 128;
  const int nbP = nb4 < 2048 ? nb4 : 2048;   // persistent agg grid: 8 blocks/CU full residency
  const int nwaves = nbP * 4;
  dim3 blk(256);

  const int Kin[3] = {64, 256, 256};
  for (int i = 0; i < 3; ++i) {
    if (i == 0) {
      gemm2_k<1><<<nbg, 512, 0, stream>>>(xb, 128, wb[0], wbp, proj_b, featB,
                                          n, 64, a_s[0], a_d[0], asrcN, adstN);
    } else {
      gemm2_k<0><<<nbg, 512, 0, stream>>>(hA, 256, wb[i], nullptr, nullptr, featB,
                                          n, Kin[i], a_s[i], a_d[i], asrcN, adstN);
    }
    edge_ex2_k<<<(EE + 255) / 256, 256, 0, stream>>>(col, dst2, asrcN, adstN, exT, eep, EE);
    if (i < 2) {
      gat_agg5_k<0><<<nbP, blk, 0, stream>>>(featB, exT, eep, rowptr, col, bb[i], gg[i], be[i],
                                             (void*)hA, n, nwaves);
    } else {
      gat_agg5_k<1><<<nbP, blk, 0, stream>>>(featB, exT, eep, rowptr, col, bb[i], gg[i], be[i],
                                             (void*)hfinal, n, nwaves);
    }
  }

  // ---- value head ----
  value_head_k<<<nb4, blk, 0, stream>>>(hfinal, vw1, vb1, vw2, vb2, outp, n);
}

// Round 11
// 417.534 us; speedup vs baseline: 1.0513x; 1.0513x over previous
//
#include <hip/hip_runtime.h>

typedef unsigned short u16;
typedef u16 u16x4 __attribute__((ext_vector_type(4)));
typedef short short8 __attribute__((ext_vector_type(8)));
typedef float f32x4 __attribute__((ext_vector_type(4)));

__device__ __forceinline__ float elu_f(float x) { return x > 0.f ? x : expm1f(x); }
__device__ __forceinline__ float lrelu_f(float x) { return x > 0.f ? x : 0.2f * x; }

__device__ __forceinline__ u16 f2b(float f) {
  union { float f; unsigned u; } v; v.f = f;
  unsigned r = v.u + 0x7FFF + ((v.u >> 16) & 1);
  return (u16)(r >> 16);
}
__device__ __forceinline__ float b2f(u16 u) {
  union { unsigned u; float f; } v; v.u = ((unsigned)u) << 16; return v.f;
}

// ---------------- fused conversions + degree count ----------------
__global__ __launch_bounds__(256) void cvtdeg_k(const float* __restrict__ x, u16* __restrict__ xb,
                                                int nx8,
                                                const float* __restrict__ pw,
                                                const float* __restrict__ w0,
                                                const float* __restrict__ w1,
                                                const float* __restrict__ w2,
                                                u16* __restrict__ dp, u16* __restrict__ d0,
                                                u16* __restrict__ d1, u16* __restrict__ d2,
                                                const int* __restrict__ edst,
                                                int E, int n, int* __restrict__ deg) {
  int i = blockIdx.x * 256 + threadIdx.x;
  if (i < nx8) {
    int j = i * 8;
    float4 a = *reinterpret_cast<const float4*>(&x[j]);
    float4 b = *reinterpret_cast<const float4*>(&x[j + 4]);
    u16x4 o0, o1;
    o0.x = f2b(a.x); o0.y = f2b(a.y); o0.z = f2b(a.z); o0.w = f2b(a.w);
    o1.x = f2b(b.x); o1.y = f2b(b.y); o1.z = f2b(b.z); o1.w = f2b(b.w);
    *reinterpret_cast<u16x4*>(&xb[j]) = o0;
    *reinterpret_cast<u16x4*>(&xb[j + 4]) = o1;
  } else if (i < nx8 + 155648) {
    int j = i - nx8;
    if (j < 8192) dp[j] = f2b(pw[j]);
    else if (j < 24576) d0[j - 8192] = f2b(w0[j - 8192]);
    else if (j < 90112) d1[j - 24576] = f2b(w1[j - 24576]);
    else d2[j - 90112] = f2b(w2[j - 90112]);
  } else {
    int j = i - (nx8 + 155648);
    if (j < E) atomicAdd(&deg[edst[j]], 1);
    else if (j < E + n) atomicAdd(&deg[j - E], 1);  // self loop
  }
}

__global__ __launch_bounds__(256) void block_sum_k(const int* __restrict__ deg,
                                                   int* __restrict__ bsum, int n) {
  int i = blockIdx.x * 256 + threadIdx.x;
  int v = (i < n) ? deg[i] : 0;
#pragma unroll
  for (int off = 1; off < 64; off <<= 1) v += __shfl_xor(v, off);
  __shared__ int ws[4];
  if ((threadIdx.x & 63) == 0) ws[threadIdx.x >> 6] = v;
  __syncthreads();
  if (threadIdx.x == 0) bsum[blockIdx.x] = ws[0] + ws[1] + ws[2] + ws[3];
}

__global__ void scan_bsum_k(int* __restrict__ bsum, int nb) {
  __shared__ int s[1024];
  int tid = threadIdx.x;
  int v = (tid < nb) ? bsum[tid] : 0;
  s[tid] = v;
  __syncthreads();
  for (int off = 1; off < 1024; off <<= 1) {
    int t = (tid >= off) ? s[tid - off] : 0;
    __syncthreads();
    s[tid] += t;
    __syncthreads();
  }
  if (tid < nb) bsum[tid] = s[tid] - v;  // exclusive
}

__global__ __launch_bounds__(256) void block_scan_k(const int* __restrict__ deg,
                                                    const int* __restrict__ bsum,
                                                    int* __restrict__ rowptr,
                                                    int* __restrict__ cursor, int n) {
  int i = blockIdx.x * 256 + threadIdx.x;
  int lane = threadIdx.x & 63, w = threadIdx.x >> 6;
  int v = (i < n) ? deg[i] : 0;
  int x = v;
#pragma unroll
  for (int off = 1; off < 64; off <<= 1) {
    int t = __shfl_up(x, off);
    if (lane >= off) x += t;
  }
  __shared__ int ws[4];
  if (lane == 63) ws[w] = x;
  __syncthreads();
  int add = bsum[blockIdx.x];
  for (int j = 0; j < w; ++j) add += ws[j];
  int excl = x - v + add;
  if (i < n) {
    cursor[i] = excl;
    rowptr[i + 1] = excl + v;
  }
  if (i == 0) rowptr[0] = 0;
}

__global__ void scatter_k(const int* __restrict__ src, const int* __restrict__ dst,
                          int E, int n, int* __restrict__ cursor,
                          int* __restrict__ col, int* __restrict__ dst2) {
  int e = blockIdx.x * blockDim.x + threadIdx.x;
  if (e < E) {
    int d = dst[e];
    int pos = atomicAdd(&cursor[d], 1);
    col[pos] = src[e];
    dst2[pos] = d;
  } else if (e < E + n) {
    int d = e - E;
    int pos = atomicAdd(&cursor[d], 1);
    col[pos] = d;  // self loop
    dst2[pos] = d;
  }
}

// ---------------- bf16 MFMA GEMM, 128x256 tile, fused attn scores (+optional fused proj) ----------------
template <int PROJ>
__global__ __launch_bounds__(512) void gemm2_k(const u16* __restrict__ A, int lda,
                                               const u16* __restrict__ W,
                                               const u16* __restrict__ pw,
                                               const float* __restrict__ pb,
                                               u16* __restrict__ Cb,
                                               int n, int K,
                                               const float* __restrict__ a_sv,
                                               const float* __restrict__ a_dv,
                                               float* __restrict__ asrcN,
                                               float* __restrict__ adstN) {
  __shared__ char Asb[128 * 128];  // 128 rows x 128B, XOR-swizzled
  __shared__ char Bsb[256 * 128];  // 256 rows x 128B
  __shared__ char Xsb[PROJ ? 128 * 272 : 16];
  __shared__ char Psb[PROJ ? 64 * 272 : 16];
  const int t = threadIdx.x;
  const int lane = t & 63, w = t >> 6;
  const int wrow = w >> 2, wcol = w & 3;
  const int row0 = blockIdx.x * 128;

  if (PROJ) {
#pragma unroll
    for (int i = 0; i < 4; ++i) {  // xb tile: 128 rows x 256B
      int ci = i * 512 + t;
      int r = ci >> 4;
      int b = (ci & 15) << 4;
      int ar = row0 + r; ar = ar < n ? ar : n - 1;
      *reinterpret_cast<int4*>(Xsb + r * 272 + b) =
          *reinterpret_cast<const int4*>(&A[(size_t)ar * 128 + (b >> 1)]);
    }
#pragma unroll
    for (int i = 0; i < 2; ++i) {  // pw: 64 rows x 256B
      int ci = i * 512 + t;
      int r = ci >> 4;
      int b = (ci & 15) << 4;
      *reinterpret_cast<int4*>(Psb + r * 272 + b) =
          *reinterpret_cast<const int4*>(&pw[r * 128 + (b >> 1)]);
    }
    __syncthreads();
    f32x4 pacc[4];
#pragma unroll
    for (int nf = 0; nf < 4; ++nf) pacc[nf] = (f32x4){0.f, 0.f, 0.f, 0.f};
#pragma unroll
    for (int ks = 0; ks < 4; ++ks) {  // K=128
      short8 paf = *reinterpret_cast<const short8*>(
          Xsb + (w * 16 + (lane & 15)) * 272 + ks * 64 + (lane >> 4) * 16);
#pragma unroll
      for (int nf = 0; nf < 4; ++nf) {
        short8 pbf = *reinterpret_cast<const short8*>(
            Psb + (nf * 16 + (lane & 15)) * 272 + ks * 64 + (lane >> 4) * 16);
        pacc[nf] = __builtin_amdgcn_mfma_f32_16x16x32_bf16(paf, pbf, pacc[nf], 0, 0, 0);
      }
    }
#pragma unroll
    for (int nf = 0; nf < 4; ++nf) {
#pragma unroll
      for (int j = 0; j < 4; ++j) {
        int rl = w * 16 + (lane >> 4) * 4 + j;
        int cg = nf * 16 + (lane & 15);
        u16 bv = f2b(elu_f(pacc[nf][j] + pb[cg]));
        *reinterpret_cast<u16*>(Asb + rl * 128 + ((cg * 2) ^ ((rl & 7) << 4))) = bv;
      }
    }
  }

  f32x4 acc[4][4];
#pragma unroll
  for (int m = 0; m < 4; ++m)
#pragma unroll
    for (int nf = 0; nf < 4; ++nf) acc[m][nf] = (f32x4){0.f, 0.f, 0.f, 0.f};

  for (int k0 = 0; k0 < K; k0 += 64) {
    if (!PROJ) {
#pragma unroll
      for (int i = 0; i < 2; ++i) {
        int ci = i * 512 + t;
        int r = ci >> 3;
        int b = (ci & 7) << 4;
        int sw = b ^ ((r & 7) << 4);
        int ar = row0 + r; ar = ar < n ? ar : n - 1;
        int4 av = *reinterpret_cast<const int4*>(&A[(size_t)ar * lda + k0 + (b >> 1)]);
        *reinterpret_cast<int4*>(Asb + r * 128 + sw) = av;
      }
    }
#pragma unroll
    for (int i = 0; i < 4; ++i) {
      int ci = i * 512 + t;
      int r = ci >> 3;
      int b = (ci & 7) << 4;
      int sw = b ^ ((r & 7) << 4);
      int4 wv = *reinterpret_cast<const int4*>(&W[(size_t)r * K + k0 + (b >> 1)]);
      *reinterpret_cast<int4*>(Bsb + r * 128 + sw) = wv;
    }
    __syncthreads();
#pragma unroll
    for (int ks = 0; ks < 2; ++ks) {
      short8 af[4], bf[4];
      int kb = ks * 64 + ((lane >> 4) << 4);
#pragma unroll
      for (int m = 0; m < 4; ++m) {
        int r = wrow * 64 + m * 16 + (lane & 15);
        af[m] = *reinterpret_cast<const short8*>(Asb + r * 128 + (kb ^ ((r & 7) << 4)));
      }
#pragma unroll
      for (int nf = 0; nf < 4; ++nf) {
        int r = wcol * 64 + nf * 16 + (lane & 15);
        bf[nf] = *reinterpret_cast<const short8*>(Bsb + r * 128 + (kb ^ ((r & 7) << 4)));
      }
#pragma unroll
      for (int m = 0; m < 4; ++m)
#pragma unroll
        for (int nf = 0; nf < 4; ++nf)
          acc[m][nf] = __builtin_amdgcn_mfma_f32_16x16x32_bf16(af[m], bf[nf], acc[m][nf], 0, 0, 0);
    }
    __syncthreads();
  }
#pragma unroll
  for (int m = 0; m < 4; ++m) {
#pragma unroll
    for (int j = 0; j < 4; ++j) {
      int rg = row0 + wrow * 64 + m * 16 + (lane >> 4) * 4 + j;
      if (rg >= n) continue;
#pragma unroll
      for (int nf = 0; nf < 4; ++nf) {
        int cg = wcol * 64 + nf * 16 + (lane & 15);
        Cb[(size_t)rg * 256 + cg] = f2b(acc[m][nf][j]);
      }
    }
  }
  {
    int h = wcol;
    int ch = lane & 15;
    float as_c[4], ad_c[4];
#pragma unroll
    for (int nf = 0; nf < 4; ++nf) {
      as_c[nf] = a_sv[h * 64 + nf * 16 + ch];
      ad_c[nf] = a_dv[h * 64 + nf * 16 + ch];
    }
#pragma unroll
    for (int m = 0; m < 4; ++m) {
#pragma unroll
      for (int j = 0; j < 4; ++j) {
        float ps = 0.f, pd = 0.f;
#pragma unroll
        for (int nf = 0; nf < 4; ++nf) {
          float v = acc[m][nf][j];
          ps += v * as_c[nf];
          pd += v * ad_c[nf];
        }
#pragma unroll
        for (int off = 1; off < 16; off <<= 1) {
          ps += __shfl_xor(ps, off);
          pd += __shfl_xor(pd, off);
        }
        int rg = row0 + wrow * 64 + m * 16 + (lane >> 4) * 4 + j;
        if ((lane & 15) == 0 && rg < n) {
          asrcN[(size_t)rg * 4 + h] = ps;
          adstN[(size_t)rg * 4 + h] = pd;
        }
      }
    }
  }
}

// ---------------- edge-parallel softmax numerators, transposed: exT[h][e] ----------------
__global__ __launch_bounds__(256) void edge_ex2_k(const int* __restrict__ col,
                                                  const int* __restrict__ dst2,
                                                  const float* __restrict__ asrcN,
                                                  const float* __restrict__ adstN,
                                                  float* __restrict__ exT, int eep, int EE) {
  int e = blockIdx.x * 256 + threadIdx.x;
  if (e >= EE) return;
  int s = col[e], d = dst2[e];
  float4 as = *reinterpret_cast<const float4*>(&asrcN[(size_t)s * 4]);
  float4 ad = *reinterpret_cast<const float4*>(&adstN[(size_t)d * 4]);
  exT[e]            = __expf(lrelu_f(as.x + ad.x));  // softmax shift-invariant; |a| <~ 5
  exT[eep + e]      = __expf(lrelu_f(as.y + ad.y));
  exT[2 * eep + e]  = __expf(lrelu_f(as.z + ad.z));
  exT[3 * eep + e]  = __expf(lrelu_f(as.w + ad.w));
}

// ---------------- fused GAT aggregation + bias + LayerNorm + ELU (R7 structure: 1 node/wave) ----------------
// MODE 0: LN(256) -> bf16 row at (u16*)out + node*256
// MODE 1: head-mean -> bias -> LN(64) -> ELU -> f32 out[node*64..]
template <int MODE>
__global__ __launch_bounds__(256) void gat_agg4_k(const u16* __restrict__ feat,
                                                  const float* __restrict__ exT, int eep,
                                                  const int* __restrict__ rowptr,
                                                  const int* __restrict__ col,
                                                  const float* __restrict__ bias,
                                                  const float* __restrict__ g,
                                                  const float* __restrict__ be,
                                                  void* __restrict__ out, int n) {
  int wave = threadIdx.x >> 6, lane = threadIdx.x & 63;
  int node = blockIdx.x * 4 + wave;
  if (node >= n) return;
  int h = lane >> 4;
  const float* exh = exT + (size_t)h * eep;
  int s0 = rowptr[node], s1 = rowptr[node + 1];
  float ax = 0.f, ay = 0.f, az = 0.f, aw = 0.f, den = 0.f;
  int e = s0;
  for (; e + 8 <= s1; e += 8) {
    int p0 = col[e + 0], p1 = col[e + 1], p2 = col[e + 2], p3 = col[e + 3];
    int q0 = col[e + 4], q1 = col[e + 5], q2 = col[e + 6], q3 = col[e + 7];
    float u0 = exh[e + 0], u1 = exh[e + 1], u2 = exh[e + 2], u3 = exh[e + 3];
    float v0 = exh[e + 4], v1 = exh[e + 5], v2 = exh[e + 6], v3 = exh[e + 7];
    u16x4 fp0 = *reinterpret_cast<const u16x4*>(&feat[(size_t)p0 * 256 + lane * 4]);
    u16x4 fp1 = *reinterpret_cast<const u16x4*>(&feat[(size_t)p1 * 256 + lane * 4]);
    u16x4 fp2 = *reinterpret_cast<const u16x4*>(&feat[(size_t)p2 * 256 + lane * 4]);
    u16x4 fp3 = *reinterpret_cast<const u16x4*>(&feat[(size_t)p3 * 256 + lane * 4]);
    u16x4 fq0 = *reinterpret_cast<const u16x4*>(&feat[(size_t)q0 * 256 + lane * 4]);
    u16x4 fq1 = *reinterpret_cast<const u16x4*>(&feat[(size_t)q1 * 256 + lane * 4]);
    u16x4 fq2 = *reinterpret_cast<const u16x4*>(&feat[(size_t)q2 * 256 + lane * 4]);
    u16x4 fq3 = *reinterpret_cast<const u16x4*>(&feat[(size_t)q3 * 256 + lane * 4]);
    den += ((u0 + u1) + (u2 + u3)) + ((v0 + v1) + (v2 + v3));
    ax += u0 * b2f(fp0.x) + u1 * b2f(fp1.x) + u2 * b2f(fp2.x) + u3 * b2f(fp3.x);
    ay += u0 * b2f(fp0.y) + u1 * b2f(fp1.y) + u2 * b2f(fp2.y) + u3 * b2f(fp3.y);
    az += u0 * b2f(fp0.z) + u1 * b2f(fp1.z) + u2 * b2f(fp2.z) + u3 * b2f(fp3.z);
    aw += u0 * b2f(fp0.w) + u1 * b2f(fp1.w) + u2 * b2f(fp2.w) + u3 * b2f(fp3.w);
    ax += v0 * b2f(fq0.x) + v1 * b2f(fq1.x) + v2 * b2f(fq2.x) + v3 * b2f(fq3.x);
    ay += v0 * b2f(fq0.y) + v1 * b2f(fq1.y) + v2 * b2f(fq2.y) + v3 * b2f(fq3.y);
    az += v0 * b2f(fq0.z) + v1 * b2f(fq1.z) + v2 * b2f(fq2.z) + v3 * b2f(fq3.z);
    aw += v0 * b2f(fq0.w) + v1 * b2f(fq1.w) + v2 * b2f(fq2.w) + v3 * b2f(fq3.w);
  }
  for (; e + 4 <= s1; e += 4) {
    int p0 = col[e + 0], p1 = col[e + 1], p2 = col[e + 2], p3 = col[e + 3];
    float u0 = exh[e + 0], u1 = exh[e + 1], u2 = exh[e + 2], u3 = exh[e + 3];
    u16x4 fp0 = *reinterpret_cast<const u16x4*>(&feat[(size_t)p0 * 256 + lane * 4]);
    u16x4 fp1 = *reinterpret_cast<const u16x4*>(&feat[(size_t)p1 * 256 + lane * 4]);
    u16x4 fp2 = *reinterpret_cast<const u16x4*>(&feat[(size_t)p2 * 256 + lane * 4]);
    u16x4 fp3 = *reinterpret_cast<const u16x4*>(&feat[(size_t)p3 * 256 + lane * 4]);
    den += (u0 + u1) + (u2 + u3);
    ax += u0 * b2f(fp0.x) + u1 * b2f(fp1.x) + u2 * b2f(fp2.x) + u3 * b2f(fp3.x);
    ay += u0 * b2f(fp0.y) + u1 * b2f(fp1.y) + u2 * b2f(fp2.y) + u3 * b2f(fp3.y);
    az += u0 * b2f(fp0.z) + u1 * b2f(fp1.z) + u2 * b2f(fp2.z) + u3 * b2f(fp3.z);
    aw += u0 * b2f(fp0.w) + u1 * b2f(fp1.w) + u2 * b2f(fp2.w) + u3 * b2f(fp3.w);
  }
  for (; e < s1; ++e) {
    int s = col[e];
    float xv = exh[e];
    den += xv;
    u16x4 f = *reinterpret_cast<const u16x4*>(&feat[(size_t)s * 256 + lane * 4]);
    ax += xv * b2f(f.x); ay += xv * b2f(f.y); az += xv * b2f(f.z); aw += xv * b2f(f.w);
  }
  float inv = 1.f / den;  // self-loop guarantees den > 0
  ax *= inv; ay *= inv; az *= inv; aw *= inv;

  if (MODE == 0) {
    float4 b4 = *reinterpret_cast<const float4*>(&bias[lane * 4]);
    float vx = ax + b4.x, vy = ay + b4.y, vz = az + b4.z, vw = aw + b4.w;
    float s = vx + vy + vz + vw;
#pragma unroll
    for (int off = 1; off < 64; off <<= 1) s += __shfl_xor(s, off);
    float mu = s * (1.f / 256.f);
    float dx = vx - mu, dy = vy - mu, dz = vz - mu, dw = vw - mu;
    float q = dx * dx + dy * dy + dz * dz + dw * dw;
#pragma unroll
    for (int off = 1; off < 64; off <<= 1) q += __shfl_xor(q, off);
    float inv2 = rsqrtf(q * (1.f / 256.f) + 1e-5f);
    float4 gg = *reinterpret_cast<const float4*>(&g[lane * 4]);
    float4 bb = *reinterpret_cast<const float4*>(&be[lane * 4]);
    u16x4 o;
    o.x = f2b(elu_f(dx * inv2 * gg.x + bb.x));
    o.y = f2b(elu_f(dy * inv2 * gg.y + bb.y));
    o.z = f2b(elu_f(dz * inv2 * gg.z + bb.z));
    o.w = f2b(elu_f(dw * inv2 * gg.w + bb.w));
    u16* rowb = (u16*)out + (size_t)node * 256;
    *reinterpret_cast<u16x4*>(&rowb[lane * 4]) = o;
  } else {
    ax += __shfl_xor(ax, 16); ax += __shfl_xor(ax, 32);
    ay += __shfl_xor(ay, 16); ay += __shfl_xor(ay, 32);
    az += __shfl_xor(az, 16); az += __shfl_xor(az, 32);
    aw += __shfl_xor(aw, 16); aw += __shfl_xor(aw, 32);
    int qd = lane & 15;
    float4 b4 = *reinterpret_cast<const float4*>(&bias[qd * 4]);
    float vx = 0.25f * ax + b4.x, vy = 0.25f * ay + b4.y;
    float vz = 0.25f * az + b4.z, vw = 0.25f * aw + b4.w;
    float s = vx + vy + vz + vw;
#pragma unroll
    for (int off = 1; off < 64; off <<= 1) s += __shfl_xor(s, off);
    float mu = s * (1.f / 256.f);
    float dx = vx - mu, dy = vy - mu, dz = vz - mu, dw = vw - mu;
    float q = dx * dx + dy * dy + dz * dz + dw * dw;
#pragma unroll
    for (int off = 1; off < 64; off <<= 1) q += __shfl_xor(q, off);
    float inv2 = rsqrtf(q * (1.f / 256.f) + 1e-5f);
    if (lane < 16) {
      float4 gg = *reinterpret_cast<const float4*>(&g[qd * 4]);
      float4 bb = *reinterpret_cast<const float4*>(&be[qd * 4]);
      float4 o;
      o.x = elu_f(dx * inv2 * gg.x + bb.x);
      o.y = elu_f(dy * inv2 * gg.y + bb.y);
      o.z = elu_f(dz * inv2 * gg.z + bb.z);
      o.w = elu_f(dw * inv2 * gg.w + bb.w);
      *reinterpret_cast<float4*>(&((float*)out)[(size_t)node * 64 + qd * 4]) = o;
    }
  }
}

// ---------------- value head: out[n,4] ----------------
__global__ __launch_bounds__(256) void value_head_k(const float* __restrict__ hh,
                                                    const float* __restrict__ vw1,
                                                    const float* __restrict__ vb1,
                                                    const float* __restrict__ vw2,
                                                    const float* __restrict__ vb2,
                                                    float* __restrict__ out, int n) {
  __shared__ float w1s[32 * 65];
  __shared__ float hs[4][64];
  __shared__ float vs[4][33];
  int tid = threadIdx.x;
  for (int i = tid; i < 2048; i += 256) w1s[(i >> 6) * 65 + (i & 63)] = vw1[i];
  int wave = tid >> 6, lane = tid & 63;
  int node = blockIdx.x * 4 + wave;
  int nc = node < n ? node : n - 1;
  hs[wave][lane] = hh[(size_t)nc * 64 + lane];
  __syncthreads();
  int j = lane & 31, half = lane >> 5;
  float p = 0.f;
#pragma unroll
  for (int c = 0; c < 32; ++c) p += hs[wave][half * 32 + c] * w1s[j * 65 + half * 32 + c];
  p += __shfl_xor(p, 32);
  float v = elu_f(p + vb1[j]);
  if (half == 0) vs[wave][j] = v;
  __syncthreads();
  if (lane < 4 && node < n) {
    float o = vb2[lane];
#pragma unroll
    for (int jj = 0; jj < 32; ++jj) o += vs[wave][jj] * vw2[lane * 32 + jj];
    out[(size_t)node * 4 + lane] = o;
  }
}

extern "C" void kernel_launch(void* const* d_in, const int* in_sizes, int n_in,
                              void* d_out, int out_size, void* d_ws, size_t ws_size,
                              hipStream_t stream) {
  const float* x      = (const float*)d_in[0];
  const int*   esrc   = (const int*)d_in[1];
  const int*   edst   = (const int*)d_in[2];
  const float* proj_w = (const float*)d_in[3];
  const float* proj_b = (const float*)d_in[4];
  const float* w[3]   = {(const float*)d_in[5],  (const float*)d_in[11], (const float*)d_in[17]};
  const float* a_s[3] = {(const float*)d_in[6],  (const float*)d_in[12], (const float*)d_in[18]};
  const float* a_d[3] = {(const float*)d_in[7],  (const float*)d_in[13], (const float*)d_in[19]};
  const float* bb[3]  = {(const float*)d_in[8],  (const float*)d_in[14], (const float*)d_in[20]};
  const float* gg[3]  = {(const float*)d_in[9],  (const float*)d_in[15], (const float*)d_in[21]};
  const float* be[3]  = {(const float*)d_in[10], (const float*)d_in[16], (const float*)d_in[22]};
  const float* vw1 = (const float*)d_in[23];
  const float* vb1 = (const float*)d_in[24];
  const float* vw2 = (const float*)d_in[25];
  const float* vb2 = (const float*)d_in[26];
  float* outp = (float*)d_out;

  const int n = in_sizes[0] / 128;
  const int E = in_sizes[1];
  const int EE = E + n;
  const int eep = (EE + 255) & ~255;
  const int nbl = (n + 255) / 256;

  // ---- workspace layout ----
  char* p = (char*)d_ws;
  auto alloc = [&](size_t bytes) { char* r = p; p += (bytes + 255) & ~(size_t)255; return r; };
  u16*   hA    = (u16*)alloc((size_t)n * 512);     // packed bf16 [n,256]; hfinal f32 [n,64] later
  u16*   featB = (u16*)alloc((size_t)n * 512);     // bf16 [n,256] gemm output
  u16*   xb    = (u16*)alloc((size_t)n * 256);     // bf16 [n,128] input x (own buffer)
  float* exT   = (float*)alloc((size_t)eep * 16);  // transposed numerators [4][eep]
  float* asrcN = (float*)alloc((size_t)n * 16);
  float* adstN = (float*)alloc((size_t)n * 16);
  u16* wbp = (u16*)alloc(64 * 128 * 2);
  u16* wb[3];
  wb[0] = (u16*)alloc(256 * 64 * 2);
  wb[1] = (u16*)alloc(256 * 256 * 2);
  wb[2] = (u16*)alloc(256 * 256 * 2);
  int* deg    = (int*)alloc((size_t)n * 4);
  int* rowptr = (int*)alloc((size_t)(n + 1) * 4);
  int* cursor = (int*)alloc((size_t)n * 4);
  int* col    = (int*)alloc((size_t)EE * 4);
  int* dst2   = (int*)alloc((size_t)EE * 4);
  int* bsum   = (int*)alloc((size_t)nbl * 4);
  float* hfinal = (float*)hA;  // f32 [n,64]; hA dead after layer-2 gemm reads it

  // ---- CSR build + conversions ----
  hipMemsetAsync(deg, 0, (size_t)n * sizeof(int), stream);
  const int nx8 = n * 16;
  cvtdeg_k<<<(nx8 + 155648 + EE + 255) / 256, 256, 0, stream>>>(
      x, xb, nx8, proj_w, w[0], w[1], w[2], wbp, wb[0], wb[1], wb[2], edst, E, n, deg);
  block_sum_k<<<nbl, 256, 0, stream>>>(deg, bsum, n);
  scan_bsum_k<<<1, 1024, 0, stream>>>(bsum, nbl);
  block_scan_k<<<nbl, 256, 0, stream>>>(deg, bsum, rowptr, cursor, n);
  scatter_k<<<(EE + 255) / 256, 256, 0, stream>>>(esrc, edst, E, n, cursor, col, dst2);

  const int nb4 = (n + 3) / 4;
  const int nbg = (n + 127) / 128;
  dim3 blk(256);

  const int Kin[3] = {64, 256, 256};
  for (int i = 0; i < 3; ++i) {
    if (i == 0) {
      gemm2_k<1><<<nbg, 512, 0, stream>>>(xb, 128, wb[0], wbp, proj_b, featB,
                                          n, 64, a_s[0], a_d[0], asrcN, adstN);
    } else {
      gemm2_k<0><<<nbg, 512, 0, stream>>>(hA, 256, wb[i], nullptr, nullptr, featB,
                                          n, Kin[i], a_s[i], a_d[i], asrcN, adstN);
    }
    edge_ex2_k<<<(EE + 255) / 256, 256, 0, stream>>>(col, dst2, asrcN, adstN, exT, eep, EE);
    if (i < 2) {
      gat_agg4_k<0><<<nb4, blk, 0, stream>>>(featB, exT, eep, rowptr, col, bb[i], gg[i], be[i],
                                             (void*)hA, n);
    } else {
      gat_agg4_k<1><<<nb4, blk, 0, stream>>>(featB, exT, eep, rowptr, col, bb[i], gg[i], be[i],
                                             (void*)hfinal, n);
    }
  }

  // ---- value head ----
  value_head_k<<<nb4, blk, 0, stream>>>(hfinal, vw1, vb1, vw2, vb2, outp, n);
}

// Round 12
// 415.669 us; speedup vs baseline: 1.0560x; 1.0045x over previous
//
#include <hip/hip_runtime.h>

typedef unsigned short u16;
typedef u16 u16x4 __attribute__((ext_vector_type(4)));
typedef short short8 __attribute__((ext_vector_type(8)));
typedef float f32x4 __attribute__((ext_vector_type(4)));

__device__ __forceinline__ float elu_f(float x) { return x > 0.f ? x : expm1f(x); }
__device__ __forceinline__ float lrelu_f(float x) { return x > 0.f ? x : 0.2f * x; }

__device__ __forceinline__ u16 f2b(float f) {
  union { float f; unsigned u; } v; v.f = f;
  unsigned r = v.u + 0x7FFF + ((v.u >> 16) & 1);
  return (u16)(r >> 16);
}
__device__ __forceinline__ float b2f(u16 u) {
  union { unsigned u; float f; } v; v.u = ((unsigned)u) << 16; return v.f;
}

// ---------------- fused conversions + degree count ----------------
__global__ __launch_bounds__(256) void cvtdeg_k(const float* __restrict__ x, u16* __restrict__ xb,
                                                int nx8,
                                                const float* __restrict__ pw,
                                                const float* __restrict__ w0,
                                                const float* __restrict__ w1,
                                                const float* __restrict__ w2,
                                                u16* __restrict__ dp, u16* __restrict__ d0,
                                                u16* __restrict__ d1, u16* __restrict__ d2,
                                                const int* __restrict__ edst,
                                                int E, int n, int* __restrict__ deg) {
  int i = blockIdx.x * 256 + threadIdx.x;
  if (i < nx8) {
    int j = i * 8;
    float4 a = *reinterpret_cast<const float4*>(&x[j]);
    float4 b = *reinterpret_cast<const float4*>(&x[j + 4]);
    u16x4 o0, o1;
    o0.x = f2b(a.x); o0.y = f2b(a.y); o0.z = f2b(a.z); o0.w = f2b(a.w);
    o1.x = f2b(b.x); o1.y = f2b(b.y); o1.z = f2b(b.z); o1.w = f2b(b.w);
    *reinterpret_cast<u16x4*>(&xb[j]) = o0;
    *reinterpret_cast<u16x4*>(&xb[j + 4]) = o1;
  } else if (i < nx8 + 155648) {
    int j = i - nx8;
    if (j < 8192) dp[j] = f2b(pw[j]);
    else if (j < 24576) d0[j - 8192] = f2b(w0[j - 8192]);
    else if (j < 90112) d1[j - 24576] = f2b(w1[j - 24576]);
    else d2[j - 90112] = f2b(w2[j - 90112]);
  } else {
    int j = i - (nx8 + 155648);
    if (j < E) atomicAdd(&deg[edst[j]], 1);
    else if (j < E + n) atomicAdd(&deg[j - E], 1);  // self loop
  }
}

__global__ __launch_bounds__(256) void block_sum_k(const int* __restrict__ deg,
                                                   int* __restrict__ bsum, int n) {
  int i = blockIdx.x * 256 + threadIdx.x;
  int v = (i < n) ? deg[i] : 0;
#pragma unroll
  for (int off = 1; off < 64; off <<= 1) v += __shfl_xor(v, off);
  __shared__ int ws[4];
  if ((threadIdx.x & 63) == 0) ws[threadIdx.x >> 6] = v;
  __syncthreads();
  if (threadIdx.x == 0) bsum[blockIdx.x] = ws[0] + ws[1] + ws[2] + ws[3];
}

__global__ void scan_bsum_k(int* __restrict__ bsum, int nb) {
  __shared__ int s[1024];
  int tid = threadIdx.x;
  int v = (tid < nb) ? bsum[tid] : 0;
  s[tid] = v;
  __syncthreads();
  for (int off = 1; off < 1024; off <<= 1) {
    int t = (tid >= off) ? s[tid - off] : 0;
    __syncthreads();
    s[tid] += t;
    __syncthreads();
  }
  if (tid < nb) bsum[tid] = s[tid] - v;  // exclusive
}

__global__ __launch_bounds__(256) void block_scan_k(const int* __restrict__ deg,
                                                    const int* __restrict__ bsum,
                                                    int* __restrict__ rowptr,
                                                    int* __restrict__ cursor, int n) {
  int i = blockIdx.x * 256 + threadIdx.x;
  int lane = threadIdx.x & 63, w = threadIdx.x >> 6;
  int v = (i < n) ? deg[i] : 0;
  int x = v;
#pragma unroll
  for (int off = 1; off < 64; off <<= 1) {
    int t = __shfl_up(x, off);
    if (lane >= off) x += t;
  }
  __shared__ int ws[4];
  if (lane == 63) ws[w] = x;
  __syncthreads();
  int add = bsum[blockIdx.x];
  for (int j = 0; j < w; ++j) add += ws[j];
  int excl = x - v + add;
  if (i < n) {
    cursor[i] = excl;
    rowptr[i + 1] = excl + v;
  }
  if (i == 0) rowptr[0] = 0;
}

// ---------------- scatter with 4-way atomic ILP ----------------
__global__ __launch_bounds__(256) void scatter4_k(const int* __restrict__ src,
                                                  const int* __restrict__ dst,
                                                  int E, int EE, int* __restrict__ cursor,
                                                  int* __restrict__ col, int* __restrict__ dst2) {
  int base = (blockIdx.x * 256 + threadIdx.x) * 4;
  int s[4], d[4], pos[4];
#pragma unroll
  for (int k = 0; k < 4; ++k) {
    int e = base + k;
    if (e < E) { s[k] = src[e]; d[k] = dst[e]; }
    else if (e < EE) { s[k] = d[k] = e - E; }  // self loop
    else { d[k] = -1; s[k] = 0; }
  }
#pragma unroll
  for (int k = 0; k < 4; ++k)
    if (d[k] >= 0) pos[k] = atomicAdd(&cursor[d[k]], 1);  // 4 independent, all in flight
#pragma unroll
  for (int k = 0; k < 4; ++k)
    if (d[k] >= 0) { col[pos[k]] = s[k]; dst2[pos[k]] = d[k]; }
}

// ---------------- bf16 MFMA GEMM, 128x256 tile, fused attn scores (+optional fused proj) ----------------
template <int PROJ>
__global__ __launch_bounds__(512) void gemm2_k(const u16* __restrict__ A, int lda,
                                               const u16* __restrict__ W,
                                               const u16* __restrict__ pw,
                                               const float* __restrict__ pb,
                                               u16* __restrict__ Cb,
                                               int n, int K,
                                               const float* __restrict__ a_sv,
                                               const float* __restrict__ a_dv,
                                               float* __restrict__ asrcN,
                                               float* __restrict__ adstN) {
  __shared__ char Asb[128 * 128];  // 128 rows x 128B, XOR-swizzled
  __shared__ char Bsb[256 * 128];  // 256 rows x 128B
  __shared__ char Xsb[PROJ ? 128 * 272 : 16];
  __shared__ char Psb[PROJ ? 64 * 272 : 16];
  const int t = threadIdx.x;
  const int lane = t & 63, w = t >> 6;
  const int wrow = w >> 2, wcol = w & 3;
  const int row0 = blockIdx.x * 128;

  if (PROJ) {
#pragma unroll
    for (int i = 0; i < 4; ++i) {  // xb tile: 128 rows x 256B
      int ci = i * 512 + t;
      int r = ci >> 4;
      int b = (ci & 15) << 4;
      int ar = row0 + r; ar = ar < n ? ar : n - 1;
      *reinterpret_cast<int4*>(Xsb + r * 272 + b) =
          *reinterpret_cast<const int4*>(&A[(size_t)ar * 128 + (b >> 1)]);
    }
#pragma unroll
    for (int i = 0; i < 2; ++i) {  // pw: 64 rows x 256B
      int ci = i * 512 + t;
      int r = ci >> 4;
      int b = (ci & 15) << 4;
      *reinterpret_cast<int4*>(Psb + r * 272 + b) =
          *reinterpret_cast<const int4*>(&pw[r * 128 + (b >> 1)]);
    }
    __syncthreads();
    f32x4 pacc[4];
#pragma unroll
    for (int nf = 0; nf < 4; ++nf) pacc[nf] = (f32x4){0.f, 0.f, 0.f, 0.f};
#pragma unroll
    for (int ks = 0; ks < 4; ++ks) {  // K=128
      short8 paf = *reinterpret_cast<const short8*>(
          Xsb + (w * 16 + (lane & 15)) * 272 + ks * 64 + (lane >> 4) * 16);
#pragma unroll
      for (int nf = 0; nf < 4; ++nf) {
        short8 pbf = *reinterpret_cast<const short8*>(
            Psb + (nf * 16 + (lane & 15)) * 272 + ks * 64 + (lane >> 4) * 16);
        pacc[nf] = __builtin_amdgcn_mfma_f32_16x16x32_bf16(paf, pbf, pacc[nf], 0, 0, 0);
      }
    }
#pragma unroll
    for (int nf = 0; nf < 4; ++nf) {
#pragma unroll
      for (int j = 0; j < 4; ++j) {
        int rl = w * 16 + (lane >> 4) * 4 + j;
        int cg = nf * 16 + (lane & 15);
        u16 bv = f2b(elu_f(pacc[nf][j] + pb[cg]));
        *reinterpret_cast<u16*>(Asb + rl * 128 + ((cg * 2) ^ ((rl & 7) << 4))) = bv;
      }
    }
  }

  f32x4 acc[4][4];
#pragma unroll
  for (int m = 0; m < 4; ++m)
#pragma unroll
    for (int nf = 0; nf < 4; ++nf) acc[m][nf] = (f32x4){0.f, 0.f, 0.f, 0.f};

  for (int k0 = 0; k0 < K; k0 += 64) {
    if (!PROJ) {
#pragma unroll
      for (int i = 0; i < 2; ++i) {
        int ci = i * 512 + t;
        int r = ci >> 3;
        int b = (ci & 7) << 4;
        int sw = b ^ ((r & 7) << 4);
        int ar = row0 + r; ar = ar < n ? ar : n - 1;
        int4 av = *reinterpret_cast<const int4*>(&A[(size_t)ar * lda + k0 + (b >> 1)]);
        *reinterpret_cast<int4*>(Asb + r * 128 + sw) = av;
      }
    }
#pragma unroll
    for (int i = 0; i < 4; ++i) {
      int ci = i * 512 + t;
      int r = ci >> 3;
      int b = (ci & 7) << 4;
      int sw = b ^ ((r & 7) << 4);
      int4 wv = *reinterpret_cast<const int4*>(&W[(size_t)r * K + k0 + (b >> 1)]);
      *reinterpret_cast<int4*>(Bsb + r * 128 + sw) = wv;
    }
    __syncthreads();
#pragma unroll
    for (int ks = 0; ks < 2; ++ks) {
      short8 af[4], bf[4];
      int kb = ks * 64 + ((lane >> 4) << 4);
#pragma unroll
      for (int m = 0; m < 4; ++m) {
        int r = wrow * 64 + m * 16 + (lane & 15);
        af[m] = *reinterpret_cast<const short8*>(Asb + r * 128 + (kb ^ ((r & 7) << 4)));
      }
#pragma unroll
      for (int nf = 0; nf < 4; ++nf) {
        int r = wcol * 64 + nf * 16 + (lane & 15);
        bf[nf] = *reinterpret_cast<const short8*>(Bsb + r * 128 + (kb ^ ((r & 7) << 4)));
      }
#pragma unroll
      for (int m = 0; m < 4; ++m)
#pragma unroll
        for (int nf = 0; nf < 4; ++nf)
          acc[m][nf] = __builtin_amdgcn_mfma_f32_16x16x32_bf16(af[m], bf[nf], acc[m][nf], 0, 0, 0);
    }
    __syncthreads();
  }
#pragma unroll
  for (int m = 0; m < 4; ++m) {
#pragma unroll
    for (int j = 0; j < 4; ++j) {
      int rg = row0 + wrow * 64 + m * 16 + (lane >> 4) * 4 + j;
      if (rg >= n) continue;
#pragma unroll
      for (int nf = 0; nf < 4; ++nf) {
        int cg = wcol * 64 + nf * 16 + (lane & 15);
        Cb[(size_t)rg * 256 + cg] = f2b(acc[m][nf][j]);
      }
    }
  }
  {
    int h = wcol;
    int ch = lane & 15;
    float as_c[4], ad_c[4];
#pragma unroll
    for (int nf = 0; nf < 4; ++nf) {
      as_c[nf] = a_sv[h * 64 + nf * 16 + ch];
      ad_c[nf] = a_dv[h * 64 + nf * 16 + ch];
    }
#pragma unroll
    for (int m = 0; m < 4; ++m) {
#pragma unroll
      for (int j = 0; j < 4; ++j) {
        float ps = 0.f, pd = 0.f;
#pragma unroll
        for (int nf = 0; nf < 4; ++nf) {
          float v = acc[m][nf][j];
          ps += v * as_c[nf];
          pd += v * ad_c[nf];
        }
#pragma unroll
        for (int off = 1; off < 16; off <<= 1) {
          ps += __shfl_xor(ps, off);
          pd += __shfl_xor(pd, off);
        }
        int rg = row0 + wrow * 64 + m * 16 + (lane >> 4) * 4 + j;
        if ((lane & 15) == 0 && rg < n) {
          asrcN[(size_t)rg * 4 + h] = ps;
          adstN[(size_t)rg * 4 + h] = pd;
        }
      }
    }
  }
}

// ---------------- edge-parallel softmax numerators, transposed: exT[h][e] ----------------
__global__ __launch_bounds__(256) void edge_ex2_k(const int* __restrict__ col,
                                                  const int* __restrict__ dst2,
                                                  const float* __restrict__ asrcN,
                                                  const float* __restrict__ adstN,
                                                  float* __restrict__ exT, int eep, int EE) {
  int e = blockIdx.x * 256 + threadIdx.x;
  if (e >= EE) return;
  int s = col[e], d = dst2[e];
  float4 as = *reinterpret_cast<const float4*>(&asrcN[(size_t)s * 4]);
  float4 ad = *reinterpret_cast<const float4*>(&adstN[(size_t)d * 4]);
  exT[e]            = __expf(lrelu_f(as.x + ad.x));  // softmax shift-invariant; |a| <~ 5
  exT[eep + e]      = __expf(lrelu_f(as.y + ad.y));
  exT[2 * eep + e]  = __expf(lrelu_f(as.z + ad.z));
  exT[3 * eep + e]  = __expf(lrelu_f(as.w + ad.w));
}

// ---------------- fused GAT aggregation + bias + LayerNorm + ELU (1 node/wave) ----------------
// MODE 0: LN(256) -> bf16 row at (u16*)out + node*256
// MODE 1: head-mean -> bias -> LN(64) -> ELU -> f32 out[node*64..]
template <int MODE>
__global__ __launch_bounds__(256) void gat_agg4_k(const u16* __restrict__ feat,
                                                  const float* __restrict__ exT, int eep,
                                                  const int* __restrict__ rowptr,
                                                  const int* __restrict__ col,
                                                  const float* __restrict__ bias,
                                                  const float* __restrict__ g,
                                                  const float* __restrict__ be,
                                                  void* __restrict__ out, int n) {
  int wave = threadIdx.x >> 6, lane = threadIdx.x & 63;
  int node = blockIdx.x * 4 + wave;
  if (node >= n) return;
  int h = lane >> 4;
  const float* exh = exT + (size_t)h * eep;
  int s0 = rowptr[node], s1 = rowptr[node + 1];
  float ax = 0.f, ay = 0.f, az = 0.f, aw = 0.f, den = 0.f;
  int e = s0;
  for (; e + 8 <= s1; e += 8) {
    int p0 = col[e + 0], p1 = col[e + 1], p2 = col[e + 2], p3 = col[e + 3];
    int q0 = col[e + 4], q1 = col[e + 5], q2 = col[e + 6], q3 = col[e + 7];
    float u0 = exh[e + 0], u1 = exh[e + 1], u2 = exh[e + 2], u3 = exh[e + 3];
    float v0 = exh[e + 4], v1 = exh[e + 5], v2 = exh[e + 6], v3 = exh[e + 7];
    u16x4 fp0 = *reinterpret_cast<const u16x4*>(&feat[(size_t)p0 * 256 + lane * 4]);
    u16x4 fp1 = *reinterpret_cast<const u16x4*>(&feat[(size_t)p1 * 256 + lane * 4]);
    u16x4 fp2 = *reinterpret_cast<const u16x4*>(&feat[(size_t)p2 * 256 + lane * 4]);
    u16x4 fp3 = *reinterpret_cast<const u16x4*>(&feat[(size_t)p3 * 256 + lane * 4]);
    u16x4 fq0 = *reinterpret_cast<const u16x4*>(&feat[(size_t)q0 * 256 + lane * 4]);
    u16x4 fq1 = *reinterpret_cast<const u16x4*>(&feat[(size_t)q1 * 256 + lane * 4]);
    u16x4 fq2 = *reinterpret_cast<const u16x4*>(&feat[(size_t)q2 * 256 + lane * 4]);
    u16x4 fq3 = *reinterpret_cast<const u16x4*>(&feat[(size_t)q3 * 256 + lane * 4]);
    den += ((u0 + u1) + (u2 + u3)) + ((v0 + v1) + (v2 + v3));
    ax += u0 * b2f(fp0.x) + u1 * b2f(fp1.x) + u2 * b2f(fp2.x) + u3 * b2f(fp3.x);
    ay += u0 * b2f(fp0.y) + u1 * b2f(fp1.y) + u2 * b2f(fp2.y) + u3 * b2f(fp3.y);
    az += u0 * b2f(fp0.z) + u1 * b2f(fp1.z) + u2 * b2f(fp2.z) + u3 * b2f(fp3.z);
    aw += u0 * b2f(fp0.w) + u1 * b2f(fp1.w) + u2 * b2f(fp2.w) + u3 * b2f(fp3.w);
    ax += v0 * b2f(fq0.x) + v1 * b2f(fq1.x) + v2 * b2f(fq2.x) + v3 * b2f(fq3.x);
    ay += v0 * b2f(fq0.y) + v1 * b2f(fq1.y) + v2 * b2f(fq2.y) + v3 * b2f(fq3.y);
    az += v0 * b2f(fq0.z) + v1 * b2f(fq1.z) + v2 * b2f(fq2.z) + v3 * b2f(fq3.z);
    aw += v0 * b2f(fq0.w) + v1 * b2f(fq1.w) + v2 * b2f(fq2.w) + v3 * b2f(fq3.w);
  }
  for (; e + 4 <= s1; e += 4) {
    int p0 = col[e + 0], p1 = col[e + 1], p2 = col[e + 2], p3 = col[e + 3];
    float u0 = exh[e + 0], u1 = exh[e + 1], u2 = exh[e + 2], u3 = exh[e + 3];
    u16x4 fp0 = *reinterpret_cast<const u16x4*>(&feat[(size_t)p0 * 256 + lane * 4]);
    u16x4 fp1 = *reinterpret_cast<const u16x4*>(&feat[(size_t)p1 * 256 + lane * 4]);
    u16x4 fp2 = *reinterpret_cast<const u16x4*>(&feat[(size_t)p2 * 256 + lane * 4]);
    u16x4 fp3 = *reinterpret_cast<const u16x4*>(&feat[(size_t)p3 * 256 + lane * 4]);
    den += (u0 + u1) + (u2 + u3);
    ax += u0 * b2f(fp0.x) + u1 * b2f(fp1.x) + u2 * b2f(fp2.x) + u3 * b2f(fp3.x);
    ay += u0 * b2f(fp0.y) + u1 * b2f(fp1.y) + u2 * b2f(fp2.y) + u3 * b2f(fp3.y);
    az += u0 * b2f(fp0.z) + u1 * b2f(fp1.z) + u2 * b2f(fp2.z) + u3 * b2f(fp3.z);
    aw += u0 * b2f(fp0.w) + u1 * b2f(fp1.w) + u2 * b2f(fp2.w) + u3 * b2f(fp3.w);
  }
  for (; e < s1; ++e) {
    int s = col[e];
    float xv = exh[e];
    den += xv;
    u16x4 f = *reinterpret_cast<const u16x4*>(&feat[(size_t)s * 256 + lane * 4]);
    ax += xv * b2f(f.x); ay += xv * b2f(f.y); az += xv * b2f(f.z); aw += xv * b2f(f.w);
  }
  float inv = 1.f / den;  // self-loop guarantees den > 0
  ax *= inv; ay *= inv; az *= inv; aw *= inv;

  if (MODE == 0) {
    float4 b4 = *reinterpret_cast<const float4*>(&bias[lane * 4]);
    float vx = ax + b4.x, vy = ay + b4.y, vz = az + b4.z, vw = aw + b4.w;
    float s = vx + vy + vz + vw;
#pragma unroll
    for (int off = 1; off < 64; off <<= 1) s += __shfl_xor(s, off);
    float mu = s * (1.f / 256.f);
    float dx = vx - mu, dy = vy - mu, dz = vz - mu, dw = vw - mu;
    float q = dx * dx + dy * dy + dz * dz + dw * dw;
#pragma unroll
    for (int off = 1; off < 64; off <<= 1) q += __shfl_xor(q, off);
    float inv2 = rsqrtf(q * (1.f / 256.f) + 1e-5f);
    float4 gg = *reinterpret_cast<const float4*>(&g[lane * 4]);
    float4 bb = *reinterpret_cast<const float4*>(&be[lane * 4]);
    u16x4 o;
    o.x = f2b(elu_f(dx * inv2 * gg.x + bb.x));
    o.y = f2b(elu_f(dy * inv2 * gg.y + bb.y));
    o.z = f2b(elu_f(dz * inv2 * gg.z + bb.z));
    o.w = f2b(elu_f(dw * inv2 * gg.w + bb.w));
    u16* rowb = (u16*)out + (size_t)node * 256;
    *reinterpret_cast<u16x4*>(&rowb[lane * 4]) = o;
  } else {
    ax += __shfl_xor(ax, 16); ax += __shfl_xor(ax, 32);
    ay += __shfl_xor(ay, 16); ay += __shfl_xor(ay, 32);
    az += __shfl_xor(az, 16); az += __shfl_xor(az, 32);
    aw += __shfl_xor(aw, 16); aw += __shfl_xor(aw, 32);
    int qd = lane & 15;
    float4 b4 = *reinterpret_cast<const float4*>(&bias[qd * 4]);
    float vx = 0.25f * ax + b4.x, vy = 0.25f * ay + b4.y;
    float vz = 0.25f * az + b4.z, vw = 0.25f * aw + b4.w;
    float s = vx + vy + vz + vw;
#pragma unroll
    for (int off = 1; off < 64; off <<= 1) s += __shfl_xor(s, off);
    float mu = s * (1.f / 256.f);
    float dx = vx - mu, dy = vy - mu, dz = vz - mu, dw = vw - mu;
    float q = dx * dx + dy * dy + dz * dz + dw * dw;
#pragma unroll
    for (int off = 1; off < 64; off <<= 1) q += __shfl_xor(q, off);
    float inv2 = rsqrtf(q * (1.f / 256.f) + 1e-5f);
    if (lane < 16) {
      float4 gg = *reinterpret_cast<const float4*>(&g[qd * 4]);
      float4 bb = *reinterpret_cast<const float4*>(&be[qd * 4]);
      float4 o;
      o.x = elu_f(dx * inv2 * gg.x + bb.x);
      o.y = elu_f(dy * inv2 * gg.y + bb.y);
      o.z = elu_f(dz * inv2 * gg.z + bb.z);
      o.w = elu_f(dw * inv2 * gg.w + bb.w);
      *reinterpret_cast<float4*>(&((float*)out)[(size_t)node * 64 + qd * 4]) = o;
    }
  }
}

// ---------------- value head: out[n,4] ----------------
__global__ __launch_bounds__(256) void value_head_k(const float* __restrict__ hh,
                                                    const float* __restrict__ vw1,
                                                    const float* __restrict__ vb1,
                                                    const float* __restrict__ vw2,
                                                    const float* __restrict__ vb2,
                                                    float* __restrict__ out, int n) {
  __shared__ float w1s[32 * 65];
  __shared__ float hs[4][64];
  __shared__ float vs[4][33];
  int tid = threadIdx.x;
  for (int i = tid; i < 2048; i += 256) w1s[(i >> 6) * 65 + (i & 63)] = vw1[i];
  int wave = tid >> 6, lane = tid & 63;
  int node = blockIdx.x * 4 + wave;
  int nc = node < n ? node : n - 1;
  hs[wave][lane] = hh[(size_t)nc * 64 + lane];
  __syncthreads();
  int j = lane & 31, half = lane >> 5;
  float p = 0.f;
#pragma unroll
  for (int c = 0; c < 32; ++c) p += hs[wave][half * 32 + c] * w1s[j * 65 + half * 32 + c];
  p += __shfl_xor(p, 32);
  float v = elu_f(p + vb1[j]);
  if (half == 0) vs[wave][j] = v;
  __syncthreads();
  if (lane < 4 && node < n) {
    float o = vb2[lane];
#pragma unroll
    for (int jj = 0; jj < 32; ++jj) o += vs[wave][jj] * vw2[lane * 32 + jj];
    out[(size_t)node * 4 + lane] = o;
  }
}

extern "C" void kernel_launch(void* const* d_in, const int* in_sizes, int n_in,
                              void* d_out, int out_size, void* d_ws, size_t ws_size,
                              hipStream_t stream) {
  const float* x      = (const float*)d_in[0];
  const int*   esrc   = (const int*)d_in[1];
  const int*   edst   = (const int*)d_in[2];
  const float* proj_w = (const float*)d_in[3];
  const float* proj_b = (const float*)d_in[4];
  const float* w[3]   = {(const float*)d_in[5],  (const float*)d_in[11], (const float*)d_in[17]};
  const float* a_s[3] = {(const float*)d_in[6],  (const float*)d_in[12], (const float*)d_in[18]};
  const float* a_d[3] = {(const float*)d_in[7],  (const float*)d_in[13], (const float*)d_in[19]};
  const float* bb[3]  = {(const float*)d_in[8],  (const float*)d_in[14], (const float*)d_in[20]};
  const float* gg[3]  = {(const float*)d_in[9],  (const float*)d_in[15], (const float*)d_in[21]};
  const float* be[3]  = {(const float*)d_in[10], (const float*)d_in[16], (const float*)d_in[22]};
  const float* vw1 = (const float*)d_in[23];
  const float* vb1 = (const float*)d_in[24];
  const float* vw2 = (const float*)d_in[25];
  const float* vb2 = (const float*)d_in[26];
  float* outp = (float*)d_out;

  const int n = in_sizes[0] / 128;
  const int E = in_sizes[1];
  const int EE = E + n;
  const int eep = (EE + 255) & ~255;
  const int nbl = (n + 255) / 256;

  // ---- workspace layout ----
  char* p = (char*)d_ws;
  auto alloc = [&](size_t bytes) { char* r = p; p += (bytes + 255) & ~(size_t)255; return r; };
  u16*   hA    = (u16*)alloc((size_t)n * 512);     // packed bf16 [n,256]; hfinal f32 [n,64] later
  u16*   featB = (u16*)alloc((size_t)n * 512);     // bf16 [n,256] gemm output
  u16*   xb    = (u16*)alloc((size_t)n * 256);     // bf16 [n,128] input x (own buffer)
  float* exT   = (float*)alloc((size_t)eep * 16);  // transposed numerators [4][eep]
  float* asrcN = (float*)alloc((size_t)n * 16);
  float* adstN = (float*)alloc((size_t)n * 16);
  u16* wbp = (u16*)alloc(64 * 128 * 2);
  u16* wb[3];
  wb[0] = (u16*)alloc(256 * 64 * 2);
  wb[1] = (u16*)alloc(256 * 256 * 2);
  wb[2] = (u16*)alloc(256 * 256 * 2);
  int* deg    = (int*)alloc((size_t)n * 4);
  int* rowptr = (int*)alloc((size_t)(n + 1) * 4);
  int* cursor = (int*)alloc((size_t)n * 4);
  int* col    = (int*)alloc((size_t)EE * 4);
  int* dst2   = (int*)alloc((size_t)EE * 4);
  int* bsum   = (int*)alloc((size_t)nbl * 4);
  float* hfinal = (float*)hA;  // f32 [n,64]; hA dead after layer-2 gemm reads it

  // ---- CSR build + conversions ----
  hipMemsetAsync(deg, 0, (size_t)n * sizeof(int), stream);
  const int nx8 = n * 16;
  cvtdeg_k<<<(nx8 + 155648 + EE + 255) / 256, 256, 0, stream>>>(
      x, xb, nx8, proj_w, w[0], w[1], w[2], wbp, wb[0], wb[1], wb[2], edst, E, n, deg);
  block_sum_k<<<nbl, 256, 0, stream>>>(deg, bsum, n);
  scan_bsum_k<<<1, 1024, 0, stream>>>(bsum, nbl);
  block_scan_k<<<nbl, 256, 0, stream>>>(deg, bsum, rowptr, cursor, n);
  scatter4_k<<<(EE + 1023) / 1024, 256, 0, stream>>>(esrc, edst, E, EE, cursor, col, dst2);

  const int nb4 = (n + 3) / 4;
  const int nbg = (n + 127) / 128;
  dim3 blk(256);

  const int Kin[3] = {64, 256, 256};
  for (int i = 0; i < 3; ++i) {
    if (i == 0) {
      gemm2_k<1><<<nbg, 512, 0, stream>>>(xb, 128, wb[0], wbp, proj_b, featB,
                                          n, 64, a_s[0], a_d[0], asrcN, adstN);
    } else {
      gemm2_k<0><<<nbg, 512, 0, stream>>>(hA, 256, wb[i], nullptr, nullptr, featB,
                                          n, Kin[i], a_s[i], a_d[i], asrcN, adstN);
    }
    edge_ex2_k<<<(EE + 255) / 256, 256, 0, stream>>>(col, dst2, asrcN, adstN, exT, eep, EE);
    if (i < 2) {
      gat_agg4_k<0><<<nb4, blk, 0, stream>>>(featB, exT, eep, rowptr, col, bb[i], gg[i], be[i],
                                             (void*)hA, n);
    } else {
      gat_agg4_k<1><<<nb4, blk, 0, stream>>>(featB, exT, eep, rowptr, col, bb[i], gg[i], be[i],
                                             (void*)hfinal, n);
    }
  }

  // ---- value head ----
  value_head_k<<<nb4, blk, 0, stream>>>(hfinal, vw1, vb1, vw2, vb2, outp, n);
}

// Round 13
// 385.768 us; speedup vs baseline: 1.1378x; 1.0775x over previous
//
#include <hip/hip_runtime.h>

typedef unsigned short u16;
typedef u16 u16x4 __attribute__((ext_vector_type(4)));
typedef short short8 __attribute__((ext_vector_type(8)));
typedef float f32x4 __attribute__((ext_vector_type(4)));

__device__ __forceinline__ float elu_f(float x) { return x > 0.f ? x : expm1f(x); }
__device__ __forceinline__ float lrelu_f(float x) { return x > 0.f ? x : 0.2f * x; }

__device__ __forceinline__ u16 f2b(float f) {
  union { float f; unsigned u; } v; v.f = f;
  unsigned r = v.u + 0x7FFF + ((v.u >> 16) & 1);
  return (u16)(r >> 16);
}
__device__ __forceinline__ float b2f(u16 u) {
  union { unsigned u; float f; } v; v.u = ((unsigned)u) << 16; return v.f;
}

// ---------------- fused conversions + degree count + edge rank ----------------
__global__ __launch_bounds__(256) void cvtdeg_k(const float* __restrict__ x, u16* __restrict__ xb,
                                                int nx8,
                                                const float* __restrict__ pw,
                                                const float* __restrict__ w0,
                                                const float* __restrict__ w1,
                                                const float* __restrict__ w2,
                                                u16* __restrict__ dp, u16* __restrict__ d0,
                                                u16* __restrict__ d1, u16* __restrict__ d2,
                                                const int* __restrict__ edst,
                                                int E, int EE, int* __restrict__ deg,
                                                int* __restrict__ rank) {
  int i = blockIdx.x * 256 + threadIdx.x;
  if (i < nx8) {
    int j = i * 8;
    float4 a = *reinterpret_cast<const float4*>(&x[j]);
    float4 b = *reinterpret_cast<const float4*>(&x[j + 4]);
    u16x4 o0, o1;
    o0.x = f2b(a.x); o0.y = f2b(a.y); o0.z = f2b(a.z); o0.w = f2b(a.w);
    o1.x = f2b(b.x); o1.y = f2b(b.y); o1.z = f2b(b.z); o1.w = f2b(b.w);
    *reinterpret_cast<u16x4*>(&xb[j]) = o0;
    *reinterpret_cast<u16x4*>(&xb[j + 4]) = o1;
  } else if (i < nx8 + 155648) {
    int j = i - nx8;
    if (j < 8192) dp[j] = f2b(pw[j]);
    else if (j < 24576) d0[j - 8192] = f2b(w0[j - 8192]);
    else if (j < 90112) d1[j - 24576] = f2b(w1[j - 24576]);
    else d2[j - 90112] = f2b(w2[j - 90112]);
  } else {
    int j = i - (nx8 + 155648);
    if (j < E) rank[j] = atomicAdd(&deg[edst[j]], 1);
    else if (j < EE) rank[j] = atomicAdd(&deg[j - E], 1);  // self loop
  }
}

__global__ __launch_bounds__(256) void block_sum_k(const int* __restrict__ deg,
                                                   int* __restrict__ bsum, int n) {
  int i = blockIdx.x * 256 + threadIdx.x;
  int v = (i < n) ? deg[i] : 0;
#pragma unroll
  for (int off = 1; off < 64; off <<= 1) v += __shfl_xor(v, off);
  __shared__ int ws[4];
  if ((threadIdx.x & 63) == 0) ws[threadIdx.x >> 6] = v;
  __syncthreads();
  if (threadIdx.x == 0) bsum[blockIdx.x] = ws[0] + ws[1] + ws[2] + ws[3];
}

__global__ void scan_bsum_k(int* __restrict__ bsum, int nb) {
  __shared__ int s[1024];
  int tid = threadIdx.x;
  int v = (tid < nb) ? bsum[tid] : 0;
  s[tid] = v;
  __syncthreads();
  for (int off = 1; off < 1024; off <<= 1) {
    int t = (tid >= off) ? s[tid - off] : 0;
    __syncthreads();
    s[tid] += t;
    __syncthreads();
  }
  if (tid < nb) bsum[tid] = s[tid] - v;  // exclusive
}

__global__ __launch_bounds__(256) void block_scan_k(const int* __restrict__ deg,
                                                    const int* __restrict__ bsum,
                                                    int* __restrict__ rowptr, int n) {
  int i = blockIdx.x * 256 + threadIdx.x;
  int lane = threadIdx.x & 63, w = threadIdx.x >> 6;
  int v = (i < n) ? deg[i] : 0;
  int x = v;
#pragma unroll
  for (int off = 1; off < 64; off <<= 1) {
    int t = __shfl_up(x, off);
    if (lane >= off) x += t;
  }
  __shared__ int ws[4];
  if (lane == 63) ws[w] = x;
  __syncthreads();
  int add = bsum[blockIdx.x];
  for (int j = 0; j < w; ++j) add += ws[j];
  int excl = x - v + add;
  if (i < n) rowptr[i + 1] = excl + v;
  if (i == 0) rowptr[0] = 0;
}

// ---------------- atomic-free scatter: pos = rowptr[dst] + rank, packed int2 writes ----------------
__global__ __launch_bounds__(256) void scatterf_k(const int* __restrict__ src,
                                                  const int* __restrict__ dst,
                                                  const int* __restrict__ rank,
                                                  const int* __restrict__ rowptr,
                                                  int E, int EE, int2* __restrict__ colpk) {
  int base = (blockIdx.x * 256 + threadIdx.x) * 4;
#pragma unroll
  for (int k = 0; k < 4; ++k) {
    int e = base + k;
    if (e < EE) {
      int s, d;
      if (e < E) { s = src[e]; d = dst[e]; }
      else { s = d = e - E; }  // self loop
      int pos = rowptr[d] + rank[e];
      colpk[pos] = make_int2(s, d);
    }
  }
}

// ---------------- bf16 MFMA GEMM, 128x256 tile, fused attn scores (+optional fused proj) ----------------
template <int PROJ>
__global__ __launch_bounds__(512) void gemm2_k(const u16* __restrict__ A, int lda,
                                               const u16* __restrict__ W,
                                               const u16* __restrict__ pw,
                                               const float* __restrict__ pb,
                                               u16* __restrict__ Cb,
                                               int n, int K,
                                               const float* __restrict__ a_sv,
                                               const float* __restrict__ a_dv,
                                               float* __restrict__ asrcN,
                                               float* __restrict__ adstN) {
  __shared__ char Asb[128 * 128];  // 128 rows x 128B, XOR-swizzled
  __shared__ char Bsb[256 * 128];  // 256 rows x 128B
  __shared__ char Xsb[PROJ ? 128 * 272 : 16];
  __shared__ char Psb[PROJ ? 64 * 272 : 16];
  const int t = threadIdx.x;
  const int lane = t & 63, w = t >> 6;
  const int wrow = w >> 2, wcol = w & 3;
  const int row0 = blockIdx.x * 128;

  if (PROJ) {
#pragma unroll
    for (int i = 0; i < 4; ++i) {  // xb tile: 128 rows x 256B
      int ci = i * 512 + t;
      int r = ci >> 4;
      int b = (ci & 15) << 4;
      int ar = row0 + r; ar = ar < n ? ar : n - 1;
      *reinterpret_cast<int4*>(Xsb + r * 272 + b) =
          *reinterpret_cast<const int4*>(&A[(size_t)ar * 128 + (b >> 1)]);
    }
#pragma unroll
    for (int i = 0; i < 2; ++i) {  // pw: 64 rows x 256B
      int ci = i * 512 + t;
      int r = ci >> 4;
      int b = (ci & 15) << 4;
      *reinterpret_cast<int4*>(Psb + r * 272 + b) =
          *reinterpret_cast<const int4*>(&pw[r * 128 + (b >> 1)]);
    }
    __syncthreads();
    f32x4 pacc[4];
#pragma unroll
    for (int nf = 0; nf < 4; ++nf) pacc[nf] = (f32x4){0.f, 0.f, 0.f, 0.f};
#pragma unroll
    for (int ks = 0; ks < 4; ++ks) {  // K=128
      short8 paf = *reinterpret_cast<const short8*>(
          Xsb + (w * 16 + (lane & 15)) * 272 + ks * 64 + (lane >> 4) * 16);
#pragma unroll
      for (int nf = 0; nf < 4; ++nf) {
        short8 pbf = *reinterpret_cast<const short8*>(
            Psb + (nf * 16 + (lane & 15)) * 272 + ks * 64 + (lane >> 4) * 16);
        pacc[nf] = __builtin_amdgcn_mfma_f32_16x16x32_bf16(paf, pbf, pacc[nf], 0, 0, 0);
      }
    }
#pragma unroll
    for (int nf = 0; nf < 4; ++nf) {
#pragma unroll
      for (int j = 0; j < 4; ++j) {
        int rl = w * 16 + (lane >> 4) * 4 + j;
        int cg = nf * 16 + (lane & 15);
        u16 bv = f2b(elu_f(pacc[nf][j] + pb[cg]));
        *reinterpret_cast<u16*>(Asb + rl * 128 + ((cg * 2) ^ ((rl & 7) << 4))) = bv;
      }
    }
  }

  f32x4 acc[4][4];
#pragma unroll
  for (int m = 0; m < 4; ++m)
#pragma unroll
    for (int nf = 0; nf < 4; ++nf) acc[m][nf] = (f32x4){0.f, 0.f, 0.f, 0.f};

  for (int k0 = 0; k0 < K; k0 += 64) {
    if (!PROJ) {
#pragma unroll
      for (int i = 0; i < 2; ++i) {
        int ci = i * 512 + t;
        int r = ci >> 3;
        int b = (ci & 7) << 4;
        int sw = b ^ ((r & 7) << 4);
        int ar = row0 + r; ar = ar < n ? ar : n - 1;
        int4 av = *reinterpret_cast<const int4*>(&A[(size_t)ar * lda + k0 + (b >> 1)]);
        *reinterpret_cast<int4*>(Asb + r * 128 + sw) = av;
      }
    }
#pragma unroll
    for (int i = 0; i < 4; ++i) {
      int ci = i * 512 + t;
      int r = ci >> 3;
      int b = (ci & 7) << 4;
      int sw = b ^ ((r & 7) << 4);
      int4 wv = *reinterpret_cast<const int4*>(&W[(size_t)r * K + k0 + (b >> 1)]);
      *reinterpret_cast<int4*>(Bsb + r * 128 + sw) = wv;
    }
    __syncthreads();
#pragma unroll
    for (int ks = 0; ks < 2; ++ks) {
      short8 af[4], bf[4];
      int kb = ks * 64 + ((lane >> 4) << 4);
#pragma unroll
      for (int m = 0; m < 4; ++m) {
        int r = wrow * 64 + m * 16 + (lane & 15);
        af[m] = *reinterpret_cast<const short8*>(Asb + r * 128 + (kb ^ ((r & 7) << 4)));
      }
#pragma unroll
      for (int nf = 0; nf < 4; ++nf) {
        int r = wcol * 64 + nf * 16 + (lane & 15);
        bf[nf] = *reinterpret_cast<const short8*>(Bsb + r * 128 + (kb ^ ((r & 7) << 4)));
      }
#pragma unroll
      for (int m = 0; m < 4; ++m)
#pragma unroll
        for (int nf = 0; nf < 4; ++nf)
          acc[m][nf] = __builtin_amdgcn_mfma_f32_16x16x32_bf16(af[m], bf[nf], acc[m][nf], 0, 0, 0);
    }
    __syncthreads();
  }
#pragma unroll
  for (int m = 0; m < 4; ++m) {
#pragma unroll
    for (int j = 0; j < 4; ++j) {
      int rg = row0 + wrow * 64 + m * 16 + (lane >> 4) * 4 + j;
      if (rg >= n) continue;
#pragma unroll
      for (int nf = 0; nf < 4; ++nf) {
        int cg = wcol * 64 + nf * 16 + (lane & 15);
        Cb[(size_t)rg * 256 + cg] = f2b(acc[m][nf][j]);
      }
    }
  }
  {
    int h = wcol;
    int ch = lane & 15;
    float as_c[4], ad_c[4];
#pragma unroll
    for (int nf = 0; nf < 4; ++nf) {
      as_c[nf] = a_sv[h * 64 + nf * 16 + ch];
      ad_c[nf] = a_dv[h * 64 + nf * 16 + ch];
    }
#pragma unroll
    for (int m = 0; m < 4; ++m) {
#pragma unroll
      for (int j = 0; j < 4; ++j) {
        float ps = 0.f, pd = 0.f;
#pragma unroll
        for (int nf = 0; nf < 4; ++nf) {
          float v = acc[m][nf][j];
          ps += v * as_c[nf];
          pd += v * ad_c[nf];
        }
#pragma unroll
        for (int off = 1; off < 16; off <<= 1) {
          ps += __shfl_xor(ps, off);
          pd += __shfl_xor(pd, off);
        }
        int rg = row0 + wrow * 64 + m * 16 + (lane >> 4) * 4 + j;
        if ((lane & 15) == 0 && rg < n) {
          asrcN[(size_t)rg * 4 + h] = ps;
          adstN[(size_t)rg * 4 + h] = pd;
        }
      }
    }
  }
}

// ---------------- edge-parallel softmax numerators, transposed: exT[h][e] ----------------
__global__ __launch_bounds__(256) void edge_ex2_k(const int2* __restrict__ colpk,
                                                  const float* __restrict__ asrcN,
                                                  const float* __restrict__ adstN,
                                                  float* __restrict__ exT, int eep, int EE) {
  int e = blockIdx.x * 256 + threadIdx.x;
  if (e >= EE) return;
  int2 cd = colpk[e];
  float4 as = *reinterpret_cast<const float4*>(&asrcN[(size_t)cd.x * 4]);
  float4 ad = *reinterpret_cast<const float4*>(&adstN[(size_t)cd.y * 4]);
  exT[e]            = __expf(lrelu_f(as.x + ad.x));  // softmax shift-invariant; |a| <~ 5
  exT[eep + e]      = __expf(lrelu_f(as.y + ad.y));
  exT[2 * eep + e]  = __expf(lrelu_f(as.z + ad.z));
  exT[3 * eep + e]  = __expf(lrelu_f(as.w + ad.w));
}

// ---------------- fused GAT aggregation + bias + LayerNorm + ELU (1 node/wave) ----------------
// MODE 0: LN(256) -> bf16 row at (u16*)out + node*256
// MODE 1: head-mean -> bias -> LN(64) -> ELU -> f32 out[node*64..]
template <int MODE>
__global__ __launch_bounds__(256) void gat_agg4_k(const u16* __restrict__ feat,
                                                  const float* __restrict__ exT, int eep,
                                                  const int* __restrict__ rowptr,
                                                  const int2* __restrict__ colpk,
                                                  const float* __restrict__ bias,
                                                  const float* __restrict__ g,
                                                  const float* __restrict__ be,
                                                  void* __restrict__ out, int n) {
  int wave = threadIdx.x >> 6, lane = threadIdx.x & 63;
  int node = blockIdx.x * 4 + wave;
  if (node >= n) return;
  int h = lane >> 4;
  const float* exh = exT + (size_t)h * eep;
  int s0 = rowptr[node], s1 = rowptr[node + 1];
  float ax = 0.f, ay = 0.f, az = 0.f, aw = 0.f, den = 0.f;
  int e = s0;
  for (; e + 8 <= s1; e += 8) {
    int p0 = colpk[e + 0].x, p1 = colpk[e + 1].x, p2 = colpk[e + 2].x, p3 = colpk[e + 3].x;
    int q0 = colpk[e + 4].x, q1 = colpk[e + 5].x, q2 = colpk[e + 6].x, q3 = colpk[e + 7].x;
    float u0 = exh[e + 0], u1 = exh[e + 1], u2 = exh[e + 2], u3 = exh[e + 3];
    float v0 = exh[e + 4], v1 = exh[e + 5], v2 = exh[e + 6], v3 = exh[e + 7];
    u16x4 fp0 = *reinterpret_cast<const u16x4*>(&feat[(size_t)p0 * 256 + lane * 4]);
    u16x4 fp1 = *reinterpret_cast<const u16x4*>(&feat[(size_t)p1 * 256 + lane * 4]);
    u16x4 fp2 = *reinterpret_cast<const u16x4*>(&feat[(size_t)p2 * 256 + lane * 4]);
    u16x4 fp3 = *reinterpret_cast<const u16x4*>(&feat[(size_t)p3 * 256 + lane * 4]);
    u16x4 fq0 = *reinterpret_cast<const u16x4*>(&feat[(size_t)q0 * 256 + lane * 4]);
    u16x4 fq1 = *reinterpret_cast<const u16x4*>(&feat[(size_t)q1 * 256 + lane * 4]);
    u16x4 fq2 = *reinterpret_cast<const u16x4*>(&feat[(size_t)q2 * 256 + lane * 4]);
    u16x4 fq3 = *reinterpret_cast<const u16x4*>(&feat[(size_t)q3 * 256 + lane * 4]);
    den += ((u0 + u1) + (u2 + u3)) + ((v0 + v1) + (v2 + v3));
    ax += u0 * b2f(fp0.x) + u1 * b2f(fp1.x) + u2 * b2f(fp2.x) + u3 * b2f(fp3.x);
    ay += u0 * b2f(fp0.y) + u1 * b2f(fp1.y) + u2 * b2f(fp2.y) + u3 * b2f(fp3.y);
    az += u0 * b2f(fp0.z) + u1 * b2f(fp1.z) + u2 * b2f(fp2.z) + u3 * b2f(fp3.z);
    aw += u0 * b2f(fp0.w) + u1 * b2f(fp1.w) + u2 * b2f(fp2.w) + u3 * b2f(fp3.w);
    ax += v0 * b2f(fq0.x) + v1 * b2f(fq1.x) + v2 * b2f(fq2.x) + v3 * b2f(fq3.x);
    ay += v0 * b2f(fq0.y) + v1 * b2f(fq1.y) + v2 * b2f(fq2.y) + v3 * b2f(fq3.y);
    az += v0 * b2f(fq0.z) + v1 * b2f(fq1.z) + v2 * b2f(fq2.z) + v3 * b2f(fq3.z);
    aw += v0 * b2f(fq0.w) + v1 * b2f(fq1.w) + v2 * b2f(fq2.w) + v3 * b2f(fq3.w);
  }
  for (; e + 4 <= s1; e += 4) {
    int p0 = colpk[e + 0].x, p1 = colpk[e + 1].x, p2 = colpk[e + 2].x, p3 = colpk[e + 3].x;
    float u0 = exh[e + 0], u1 = exh[e + 1], u2 = exh[e + 2], u3 = exh[e + 3];
    u16x4 fp0 = *reinterpret_cast<const u16x4*>(&feat[(size_t)p0 * 256 + lane * 4]);
    u16x4 fp1 = *reinterpret_cast<const u16x4*>(&feat[(size_t)p1 * 256 + lane * 4]);
    u16x4 fp2 = *reinterpret_cast<const u16x4*>(&feat[(size_t)p2 * 256 + lane * 4]);
    u16x4 fp3 = *reinterpret_cast<const u16x4*>(&feat[(size_t)p3 * 256 + lane * 4]);
    den += (u0 + u1) + (u2 + u3);
    ax += u0 * b2f(fp0.x) + u1 * b2f(fp1.x) + u2 * b2f(fp2.x) + u3 * b2f(fp3.x);
    ay += u0 * b2f(fp0.y) + u1 * b2f(fp1.y) + u2 * b2f(fp2.y) + u3 * b2f(fp3.y);
    az += u0 * b2f(fp0.z) + u1 * b2f(fp1.z) + u2 * b2f(fp2.z) + u3 * b2f(fp3.z);
    aw += u0 * b2f(fp0.w) + u1 * b2f(fp1.w) + u2 * b2f(fp2.w) + u3 * b2f(fp3.w);
  }
  for (; e < s1; ++e) {
    int s = colpk[e].x;
    float xv = exh[e];
    den += xv;
    u16x4 f = *reinterpret_cast<const u16x4*>(&feat[(size_t)s * 256 + lane * 4]);
    ax += xv * b2f(f.x); ay += xv * b2f(f.y); az += xv * b2f(f.z); aw += xv * b2f(f.w);
  }
  float inv = 1.f / den;  // self-loop guarantees den > 0
  ax *= inv; ay *= inv; az *= inv; aw *= inv;

  if (MODE == 0) {
    float4 b4 = *reinterpret_cast<const float4*>(&bias[lane * 4]);
    float vx = ax + b4.x, vy = ay + b4.y, vz = az + b4.z, vw = aw + b4.w;
    float s = vx + vy + vz + vw;
#pragma unroll
    for (int off = 1; off < 64; off <<= 1) s += __shfl_xor(s, off);
    float mu = s * (1.f / 256.f);
    float dx = vx - mu, dy = vy - mu, dz = vz - mu, dw = vw - mu;
    float q = dx * dx + dy * dy + dz * dz + dw * dw;
#pragma unroll
    for (int off = 1; off < 64; off <<= 1) q += __shfl_xor(q, off);
    float inv2 = rsqrtf(q * (1.f / 256.f) + 1e-5f);
    float4 gg = *reinterpret_cast<const float4*>(&g[lane * 4]);
    float4 bb = *reinterpret_cast<const float4*>(&be[lane * 4]);
    u16x4 o;
    o.x = f2b(elu_f(dx * inv2 * gg.x + bb.x));
    o.y = f2b(elu_f(dy * inv2 * gg.y + bb.y));
    o.z = f2b(elu_f(dz * inv2 * gg.z + bb.z));
    o.w = f2b(elu_f(dw * inv2 * gg.w + bb.w));
    u16* rowb = (u16*)out + (size_t)node * 256;
    *reinterpret_cast<u16x4*>(&rowb[lane * 4]) = o;
  } else {
    ax += __shfl_xor(ax, 16); ax += __shfl_xor(ax, 32);
    ay += __shfl_xor(ay, 16); ay += __shfl_xor(ay, 32);
    az += __shfl_xor(az, 16); az += __shfl_xor(az, 32);
    aw += __shfl_xor(aw, 16); aw += __shfl_xor(aw, 32);
    int qd = lane & 15;
    float4 b4 = *reinterpret_cast<const float4*>(&bias[qd * 4]);
    float vx = 0.25f * ax + b4.x, vy = 0.25f * ay + b4.y;
    float vz = 0.25f * az + b4.z, vw = 0.25f * aw + b4.w;
    float s = vx + vy + vz + vw;
#pragma unroll
    for (int off = 1; off < 64; off <<= 1) s += __shfl_xor(s, off);
    float mu = s * (1.f / 256.f);
    float dx = vx - mu, dy = vy - mu, dz = vz - mu, dw = vw - mu;
    float q = dx * dx + dy * dy + dz * dz + dw * dw;
#pragma unroll
    for (int off = 1; off < 64; off <<= 1) q += __shfl_xor(q, off);
    float inv2 = rsqrtf(q * (1.f / 256.f) + 1e-5f);
    if (lane < 16) {
      float4 gg = *reinterpret_cast<const float4*>(&g[qd * 4]);
      float4 bb = *reinterpret_cast<const float4*>(&be[qd * 4]);
      float4 o;
      o.x = elu_f(dx * inv2 * gg.x + bb.x);
      o.y = elu_f(dy * inv2 * gg.y + bb.y);
      o.z = elu_f(dz * inv2 * gg.z + bb.z);
      o.w = elu_f(dw * inv2 * gg.w + bb.w);
      *reinterpret_cast<float4*>(&((float*)out)[(size_t)node * 64 + qd * 4]) = o;
    }
  }
}

// ---------------- value head: out[n,4] ----------------
__global__ __launch_bounds__(256) void value_head_k(const float* __restrict__ hh,
                                                    const float* __restrict__ vw1,
                                                    const float* __restrict__ vb1,
                                                    const float* __restrict__ vw2,
                                                    const float* __restrict__ vb2,
                                                    float* __restrict__ out, int n) {
  __shared__ float w1s[32 * 65];
  __shared__ float hs[4][64];
  __shared__ float vs[4][33];
  int tid = threadIdx.x;
  for (int i = tid; i < 2048; i += 256) w1s[(i >> 6) * 65 + (i & 63)] = vw1[i];
  int wave = tid >> 6, lane = tid & 63;
  int node = blockIdx.x * 4 + wave;
  int nc = node < n ? node : n - 1;
  hs[wave][lane] = hh[(size_t)nc * 64 + lane];
  __syncthreads();
  int j = lane & 31, half = lane >> 5;
  float p = 0.f;
#pragma unroll
  for (int c = 0; c < 32; ++c) p += hs[wave][half * 32 + c] * w1s[j * 65 + half * 32 + c];
  p += __shfl_xor(p, 32);
  float v = elu_f(p + vb1[j]);
  if (half == 0) vs[wave][j] = v;
  __syncthreads();
  if (lane < 4 && node < n) {
    float o = vb2[lane];
#pragma unroll
    for (int jj = 0; jj < 32; ++jj) o += vs[wave][jj] * vw2[lane * 32 + jj];
    out[(size_t)node * 4 + lane] = o;
  }
}

extern "C" void kernel_launch(void* const* d_in, const int* in_sizes, int n_in,
                              void* d_out, int out_size, void* d_ws, size_t ws_size,
                              hipStream_t stream) {
  const float* x      = (const float*)d_in[0];
  const int*   esrc   = (const int*)d_in[1];
  const int*   edst   = (const int*)d_in[2];
  const float* proj_w = (const float*)d_in[3];
  const float* proj_b = (const float*)d_in[4];
  const float* w[3]   = {(const float*)d_in[5],  (const float*)d_in[11], (const float*)d_in[17]};
  const float* a_s[3] = {(const float*)d_in[6],  (const float*)d_in[12], (const float*)d_in[18]};
  const float* a_d[3] = {(const float*)d_in[7],  (const float*)d_in[13], (const float*)d_in[19]};
  const float* bb[3]  = {(const float*)d_in[8],  (const float*)d_in[14], (const float*)d_in[20]};
  const float* gg[3]  = {(const float*)d_in[9],  (const float*)d_in[15], (const float*)d_in[21]};
  const float* be[3]  = {(const float*)d_in[10], (const float*)d_in[16], (const float*)d_in[22]};
  const float* vw1 = (const float*)d_in[23];
  const float* vb1 = (const float*)d_in[24];
  const float* vw2 = (const float*)d_in[25];
  const float* vb2 = (const float*)d_in[26];
  float* outp = (float*)d_out;

  const int n = in_sizes[0] / 128;
  const int E = in_sizes[1];
  const int EE = E + n;
  const int eep = (EE + 255) & ~255;
  const int nbl = (n + 255) / 256;

  // ---- workspace layout ----
  char* p = (char*)d_ws;
  auto alloc = [&](size_t bytes) { char* r = p; p += (bytes + 255) & ~(size_t)255; return r; };
  u16*   hA    = (u16*)alloc((size_t)n * 512);     // packed bf16 [n,256]; hfinal f32 [n,64] later
  u16*   featB = (u16*)alloc((size_t)n * 512);     // bf16 [n,256] gemm output
  u16*   xb    = (u16*)alloc((size_t)n * 256);     // bf16 [n,128] input x (own buffer)
  float* exT   = (float*)alloc((size_t)eep * 16);  // transposed numerators [4][eep]
  float* asrcN = (float*)alloc((size_t)n * 16);
  float* adstN = (float*)alloc((size_t)n * 16);
  u16* wbp = (u16*)alloc(64 * 128 * 2);
  u16* wb[3];
  wb[0] = (u16*)alloc(256 * 64 * 2);
  wb[1] = (u16*)alloc(256 * 256 * 2);
  wb[2] = (u16*)alloc(256 * 256 * 2);
  int* deg    = (int*)alloc((size_t)n * 4);
  int* rowptr = (int*)alloc((size_t)(n + 1) * 4);
  int* rank   = (int*)alloc((size_t)EE * 4);
  int2* colpk = (int2*)alloc((size_t)EE * 8);
  int* bsum   = (int*)alloc((size_t)nbl * 4);
  float* hfinal = (float*)hA;  // f32 [n,64]; hA dead after layer-2 gemm reads it

  // ---- CSR build + conversions (rank atomic fused into cvtdeg) ----
  hipMemsetAsync(deg, 0, (size_t)n * sizeof(int), stream);
  const int nx8 = n * 16;
  cvtdeg_k<<<(nx8 + 155648 + EE + 255) / 256, 256, 0, stream>>>(
      x, xb, nx8, proj_w, w[0], w[1], w[2], wbp, wb[0], wb[1], wb[2], edst, E, EE, deg, rank);
  block_sum_k<<<nbl, 256, 0, stream>>>(deg, bsum, n);
  scan_bsum_k<<<1, 1024, 0, stream>>>(bsum, nbl);
  block_scan_k<<<nbl, 256, 0, stream>>>(deg, bsum, rowptr, n);
  scatterf_k<<<(EE + 1023) / 1024, 256, 0, stream>>>(esrc, edst, rank, rowptr, E, EE, colpk);

  const int nb4 = (n + 3) / 4;
  const int nbg = (n + 127) / 128;
  dim3 blk(256);

  const int Kin[3] = {64, 256, 256};
  for (int i = 0; i < 3; ++i) {
    if (i == 0) {
      gemm2_k<1><<<nbg, 512, 0, stream>>>(xb, 128, wb[0], wbp, proj_b, featB,
                                          n, 64, a_s[0], a_d[0], asrcN, adstN);
    } else {
      gemm2_k<0><<<nbg, 512, 0, stream>>>(hA, 256, wb[i], nullptr, nullptr, featB,
                                          n, Kin[i], a_s[i], a_d[i], asrcN, adstN);
    }
    edge_ex2_k<<<(EE + 255) / 256, 256, 0, stream>>>(colpk, asrcN, adstN, exT, eep, EE);
    if (i < 2) {
      gat_agg4_k<0><<<nb4, blk, 0, stream>>>(featB, exT, eep, rowptr, colpk, bb[i], gg[i], be[i],
                                             (void*)hA, n);
    } else {
      gat_agg4_k<1><<<nb4, blk, 0, stream>>>(featB, exT, eep, rowptr, colpk, bb[i], gg[i], be[i],
                                             (void*)hfinal, n);
    }
  }

  // ---- value head ----
  value_head_k<<<nb4, blk, 0, stream>>>(hfinal, vw1, vb1, vw2, vb2, outp, n);
}

// Round 17
// 370.992 us; speedup vs baseline: 1.1832x; 1.0398x over previous
//
#include <hip/hip_runtime.h>

typedef unsigned short u16;
typedef u16 u16x4 __attribute__((ext_vector_type(4)));
typedef short short8 __attribute__((ext_vector_type(8)));
typedef float f32x4 __attribute__((ext_vector_type(4)));

__device__ __forceinline__ float elu_f(float x) { return x > 0.f ? x : expm1f(x); }
__device__ __forceinline__ float lrelu_f(float x) { return x > 0.f ? x : 0.2f * x; }

__device__ __forceinline__ u16 f2b(float f) {
  union { float f; unsigned u; } v; v.f = f;
  unsigned r = v.u + 0x7FFF + ((v.u >> 16) & 1);
  return (u16)(r >> 16);
}
__device__ __forceinline__ float b2f(u16 u) {
  union { unsigned u; float f; } v; v.u = ((unsigned)u) << 16; return v.f;
}

// ---------------- weight conversions + degree count + edge rank ----------------
__global__ __launch_bounds__(256) void cvtdeg_k(const float* __restrict__ pw,
                                                const float* __restrict__ w0,
                                                const float* __restrict__ w1,
                                                const float* __restrict__ w2,
                                                u16* __restrict__ dp, u16* __restrict__ d0,
                                                u16* __restrict__ d1, u16* __restrict__ d2,
                                                const int* __restrict__ edst,
                                                int E, int EE, int* __restrict__ deg,
                                                int* __restrict__ rank) {
  int i = blockIdx.x * 256 + threadIdx.x;
  if (i < 155648) {
    if (i < 8192) dp[i] = f2b(pw[i]);
    else if (i < 24576) d0[i - 8192] = f2b(w0[i - 8192]);
    else if (i < 90112) d1[i - 24576] = f2b(w1[i - 24576]);
    else d2[i - 90112] = f2b(w2[i - 90112]);
  } else {
    int j = i - 155648;
    if (j < E) rank[j] = atomicAdd(&deg[edst[j]], 1);
    else if (j < EE) rank[j] = atomicAdd(&deg[j - E], 1);  // self loop
  }
}

__global__ __launch_bounds__(256) void block_sum_k(const int* __restrict__ deg,
                                                   int* __restrict__ bsum, int n) {
  int i = blockIdx.x * 256 + threadIdx.x;
  int v = (i < n) ? deg[i] : 0;
#pragma unroll
  for (int off = 1; off < 64; off <<= 1) v += __shfl_xor(v, off);
  __shared__ int ws[4];
  if ((threadIdx.x & 63) == 0) ws[threadIdx.x >> 6] = v;
  __syncthreads();
  if (threadIdx.x == 0) bsum[blockIdx.x] = ws[0] + ws[1] + ws[2] + ws[3];
}

__global__ void scan_bsum_k(int* __restrict__ bsum, int nb) {
  __shared__ int s[1024];
  int tid = threadIdx.x;
  int v = (tid < nb) ? bsum[tid] : 0;
  s[tid] = v;
  __syncthreads();
  for (int off = 1; off < 1024; off <<= 1) {
    int t = (tid >= off) ? s[tid - off] : 0;
    __syncthreads();
    s[tid] += t;
    __syncthreads();
  }
  if (tid < nb) bsum[tid] = s[tid] - v;  // exclusive
}

__global__ __launch_bounds__(256) void block_scan_k(const int* __restrict__ deg,
                                                    const int* __restrict__ bsum,
                                                    int* __restrict__ rowptr, int n) {
  int i = blockIdx.x * 256 + threadIdx.x;
  int lane = threadIdx.x & 63, w = threadIdx.x >> 6;
  int v = (i < n) ? deg[i] : 0;
  int x = v;
#pragma unroll
  for (int off = 1; off < 64; off <<= 1) {
    int t = __shfl_up(x, off);
    if (lane >= off) x += t;
  }
  __shared__ int ws[4];
  if (lane == 63) ws[w] = x;
  __syncthreads();
  int add = bsum[blockIdx.x];
  for (int j = 0; j < w; ++j) add += ws[j];
  int excl = x - v + add;
  if (i < n) rowptr[i + 1] = excl + v;
  if (i == 0) rowptr[0] = 0;
}

// ---------------- atomic-free scatter: pos = rowptr[dst] + rank, packed int2 writes ----------------
__global__ __launch_bounds__(256) void scatterf_k(const int* __restrict__ src,
                                                  const int* __restrict__ dst,
                                                  const int* __restrict__ rank,
                                                  const int* __restrict__ rowptr,
                                                  int E, int EE, int2* __restrict__ colpk) {
  int base = (blockIdx.x * 256 + threadIdx.x) * 4;
#pragma unroll
  for (int k = 0; k < 4; ++k) {
    int e = base + k;
    if (e < EE) {
      int s, d;
      if (e < E) { s = src[e]; d = dst[e]; }
      else { s = d = e - E; }  // self loop
      int pos = rowptr[d] + rank[e];
      colpk[pos] = make_int2(s, d);
    }
  }
}

// ---------------- bf16 MFMA GEMM, 128x256 tile, fused attn scores (+optional fused proj) ----------------
// PROJ=1: reads f32 x directly, converts to bf16 while staging to LDS (no xb buffer).
template <int PROJ>
__global__ __launch_bounds__(512) void gemm2_k(const u16* __restrict__ A, int lda,
                                               const float* __restrict__ xf,
                                               const u16* __restrict__ W,
                                               const u16* __restrict__ pw,
                                               const float* __restrict__ pb,
                                               u16* __restrict__ Cb,
                                               int n, int K,
                                               const float* __restrict__ a_sv,
                                               const float* __restrict__ a_dv,
                                               float* __restrict__ asrcN,
                                               float* __restrict__ adstN) {
  __shared__ char Asb[128 * 128];  // 128 rows x 128B, XOR-swizzled
  __shared__ char Bsb[256 * 128];  // 256 rows x 128B
  __shared__ char Xsb[PROJ ? 128 * 272 : 16];
  __shared__ char Psb[PROJ ? 64 * 272 : 16];
  const int t = threadIdx.x;
  const int lane = t & 63, w = t >> 6;
  const int wrow = w >> 2, wcol = w & 3;
  const int row0 = blockIdx.x * 128;

  if (PROJ) {
    // stage x tile (f32 -> bf16 in-register): 128 rows x 128 f32 = 4096 float4 chunks
#pragma unroll
    for (int i = 0; i < 8; ++i) {
      int ci = i * 512 + t;
      int r = ci >> 5;               // row 0..127 (32 float4 per row)
      int c = (ci & 31) << 2;        // f32 col
      int ar = row0 + r; ar = ar < n ? ar : n - 1;
      float4 v = *reinterpret_cast<const float4*>(&xf[(size_t)ar * 128 + c]);
      u16x4 o;
      o.x = f2b(v.x); o.y = f2b(v.y); o.z = f2b(v.z); o.w = f2b(v.w);
      *reinterpret_cast<u16x4*>(Xsb + r * 272 + c * 2) = o;
    }
#pragma unroll
    for (int i = 0; i < 2; ++i) {  // pw (bf16): 64 rows x 256B
      int ci = i * 512 + t;
      int r = ci >> 4;
      int b = (ci & 15) << 4;
      *reinterpret_cast<int4*>(Psb + r * 272 + b) =
          *reinterpret_cast<const int4*>(&pw[r * 128 + (b >> 1)]);
    }
    __syncthreads();
    f32x4 pacc[4];
#pragma unroll
    for (int nf = 0; nf < 4; ++nf) pacc[nf] = (f32x4){0.f, 0.f, 0.f, 0.f};
#pragma unroll
    for (int ks = 0; ks < 4; ++ks) {  // K=128
      short8 paf = *reinterpret_cast<const short8*>(
          Xsb + (w * 16 + (lane & 15)) * 272 + ks * 64 + (lane >> 4) * 16);
#pragma unroll
      for (int nf = 0; nf < 4; ++nf) {
        short8 pbf = *reinterpret_cast<const short8*>(
            Psb + (nf * 16 + (lane & 15)) * 272 + ks * 64 + (lane >> 4) * 16);
        pacc[nf] = __builtin_amdgcn_mfma_f32_16x16x32_bf16(paf, pbf, pacc[nf], 0, 0, 0);
      }
    }
#pragma unroll
    for (int nf = 0; nf < 4; ++nf) {
#pragma unroll
      for (int j = 0; j < 4; ++j) {
        int rl = w * 16 + (lane >> 4) * 4 + j;
        int cg = nf * 16 + (lane & 15);
        u16 bv = f2b(elu_f(pacc[nf][j] + pb[cg]));
        *reinterpret_cast<u16*>(Asb + rl * 128 + ((cg * 2) ^ ((rl & 7) << 4))) = bv;
      }
    }
  }

  f32x4 acc[4][4];
#pragma unroll
  for (int m = 0; m < 4; ++m)
#pragma unroll
    for (int nf = 0; nf < 4; ++nf) acc[m][nf] = (f32x4){0.f, 0.f, 0.f, 0.f};

  for (int k0 = 0; k0 < K; k0 += 64) {
    if (!PROJ) {
#pragma unroll
      for (int i = 0; i < 2; ++i) {
        int ci = i * 512 + t;
        int r = ci >> 3;
        int b = (ci & 7) << 4;
        int sw = b ^ ((r & 7) << 4);
        int ar = row0 + r; ar = ar < n ? ar : n - 1;
        int4 av = *reinterpret_cast<const int4*>(&A[(size_t)ar * lda + k0 + (b >> 1)]);
        *reinterpret_cast<int4*>(Asb + r * 128 + sw) = av;
      }
    }
#pragma unroll
    for (int i = 0; i < 4; ++i) {
      int ci = i * 512 + t;
      int r = ci >> 3;
      int b = (ci & 7) << 4;
      int sw = b ^ ((r & 7) << 4);
      int4 wv = *reinterpret_cast<const int4*>(&W[(size_t)r * K + k0 + (b >> 1)]);
      *reinterpret_cast<int4*>(Bsb + r * 128 + sw) = wv;
    }
    __syncthreads();
#pragma unroll
    for (int ks = 0; ks < 2; ++ks) {
      short8 af[4], bf[4];
      int kb = ks * 64 + ((lane >> 4) << 4);
#pragma unroll
      for (int m = 0; m < 4; ++m) {
        int r = wrow * 64 + m * 16 + (lane & 15);
        af[m] = *reinterpret_cast<const short8*>(Asb + r * 128 + (kb ^ ((r & 7) << 4)));
      }
#pragma unroll
      for (int nf = 0; nf < 4; ++nf) {
        int r = wcol * 64 + nf * 16 + (lane & 15);
        bf[nf] = *reinterpret_cast<const short8*>(Bsb + r * 128 + (kb ^ ((r & 7) << 4)));
      }
#pragma unroll
      for (int m = 0; m < 4; ++m)
#pragma unroll
        for (int nf = 0; nf < 4; ++nf)
          acc[m][nf] = __builtin_amdgcn_mfma_f32_16x16x32_bf16(af[m], bf[nf], acc[m][nf], 0, 0, 0);
    }
    __syncthreads();
  }
#pragma unroll
  for (int m = 0; m < 4; ++m) {
#pragma unroll
    for (int j = 0; j < 4; ++j) {
      int rg = row0 + wrow * 64 + m * 16 + (lane >> 4) * 4 + j;
      if (rg >= n) continue;
#pragma unroll
      for (int nf = 0; nf < 4; ++nf) {
        int cg = wcol * 64 + nf * 16 + (lane & 15);
        Cb[(size_t)rg * 256 + cg] = f2b(acc[m][nf][j]);
      }
    }
  }
  {
    int h = wcol;
    int ch = lane & 15;
    float as_c[4], ad_c[4];
#pragma unroll
    for (int nf = 0; nf < 4; ++nf) {
      as_c[nf] = a_sv[h * 64 + nf * 16 + ch];
      ad_c[nf] = a_dv[h * 64 + nf * 16 + ch];
    }
#pragma unroll
    for (int m = 0; m < 4; ++m) {
#pragma unroll
      for (int j = 0; j < 4; ++j) {
        float ps = 0.f, pd = 0.f;
#pragma unroll
        for (int nf = 0; nf < 4; ++nf) {
          float v = acc[m][nf][j];
          ps += v * as_c[nf];
          pd += v * ad_c[nf];
        }
#pragma unroll
        for (int off = 1; off < 16; off <<= 1) {
          ps += __shfl_xor(ps, off);
          pd += __shfl_xor(pd, off);
        }
        int rg = row0 + wrow * 64 + m * 16 + (lane >> 4) * 4 + j;
        if ((lane & 15) == 0 && rg < n) {
          asrcN[(size_t)rg * 4 + h] = ps;
          adstN[(size_t)rg * 4 + h] = pd;
        }
      }
    }
  }
}

// ---------------- edge-parallel softmax numerators, transposed: exT[h][e] ----------------
__global__ __launch_bounds__(256) void edge_ex2_k(const int2* __restrict__ colpk,
                                                  const float* __restrict__ asrcN,
                                                  const float* __restrict__ adstN,
                                                  float* __restrict__ exT, int eep, int EE) {
  int e = blockIdx.x * 256 + threadIdx.x;
  if (e >= EE) return;
  int2 cd = colpk[e];
  float4 as = *reinterpret_cast<const float4*>(&asrcN[(size_t)cd.x * 4]);
  float4 ad = *reinterpret_cast<const float4*>(&adstN[(size_t)cd.y * 4]);
  exT[e]            = __expf(lrelu_f(as.x + ad.x));  // softmax shift-invariant; |a| <~ 5
  exT[eep + e]      = __expf(lrelu_f(as.y + ad.y));
  exT[2 * eep + e]  = __expf(lrelu_f(as.z + ad.z));
  exT[3 * eep + e]  = __expf(lrelu_f(as.w + ad.w));
}

// ---------------- fused GAT aggregation + bias + LayerNorm + ELU (1 node/wave) ----------------
// MODE 0: LN(256) -> bf16 row at (u16*)out + node*256
// MODE 1: head-mean -> bias -> LN(64) -> ELU -> f32 out[node*64..]
template <int MODE>
__global__ __launch_bounds__(256) void gat_agg4_k(const u16* __restrict__ feat,
                                                  const float* __restrict__ exT, int eep,
                                                  const int* __restrict__ rowptr,
                                                  const int2* __restrict__ colpk,
                                                  const float* __restrict__ bias,
                                                  const float* __restrict__ g,
                                                  const float* __restrict__ be,
                                                  void* __restrict__ out, int n) {
  int wave = threadIdx.x >> 6, lane = threadIdx.x & 63;
  int node = blockIdx.x * 4 + wave;
  if (node >= n) return;
  int h = lane >> 4;
  const float* exh = exT + (size_t)h * eep;
  int s0 = rowptr[node], s1 = rowptr[node + 1];
  float ax = 0.f, ay = 0.f, az = 0.f, aw = 0.f, den = 0.f;
  int e = s0;
  for (; e + 8 <= s1; e += 8) {
    int p0 = colpk[e + 0].x, p1 = colpk[e + 1].x, p2 = colpk[e + 2].x, p3 = colpk[e + 3].x;
    int q0 = colpk[e + 4].x, q1 = colpk[e + 5].x, q2 = colpk[e + 6].x, q3 = colpk[e + 7].x;
    float u0 = exh[e + 0], u1 = exh[e + 1], u2 = exh[e + 2], u3 = exh[e + 3];
    float v0 = exh[e + 4], v1 = exh[e + 5], v2 = exh[e + 6], v3 = exh[e + 7];
    u16x4 fp0 = *reinterpret_cast<const u16x4*>(&feat[(size_t)p0 * 256 + lane * 4]);
    u16x4 fp1 = *reinterpret_cast<const u16x4*>(&feat[(size_t)p1 * 256 + lane * 4]);
    u16x4 fp2 = *reinterpret_cast<const u16x4*>(&feat[(size_t)p2 * 256 + lane * 4]);
    u16x4 fp3 = *reinterpret_cast<const u16x4*>(&feat[(size_t)p3 * 256 + lane * 4]);
    u16x4 fq0 = *reinterpret_cast<const u16x4*>(&feat[(size_t)q0 * 256 + lane * 4]);
    u16x4 fq1 = *reinterpret_cast<const u16x4*>(&feat[(size_t)q1 * 256 + lane * 4]);
    u16x4 fq2 = *reinterpret_cast<const u16x4*>(&feat[(size_t)q2 * 256 + lane * 4]);
    u16x4 fq3 = *reinterpret_cast<const u16x4*>(&feat[(size_t)q3 * 256 + lane * 4]);
    den += ((u0 + u1) + (u2 + u3)) + ((v0 + v1) + (v2 + v3));
    ax += u0 * b2f(fp0.x) + u1 * b2f(fp1.x) + u2 * b2f(fp2.x) + u3 * b2f(fp3.x);
    ay += u0 * b2f(fp0.y) + u1 * b2f(fp1.y) + u2 * b2f(fp2.y) + u3 * b2f(fp3.y);
    az += u0 * b2f(fp0.z) + u1 * b2f(fp1.z) + u2 * b2f(fp2.z) + u3 * b2f(fp3.z);
    aw += u0 * b2f(fp0.w) + u1 * b2f(fp1.w) + u2 * b2f(fp2.w) + u3 * b2f(fp3.w);
    ax += v0 * b2f(fq0.x) + v1 * b2f(fq1.x) + v2 * b2f(fq2.x) + v3 * b2f(fq3.x);
    ay += v0 * b2f(fq0.y) + v1 * b2f(fq1.y) + v2 * b2f(fq2.y) + v3 * b2f(fq3.y);
    az += v0 * b2f(fq0.z) + v1 * b2f(fq1.z) + v2 * b2f(fq2.z) + v3 * b2f(fq3.z);
    aw += v0 * b2f(fq0.w) + v1 * b2f(fq1.w) + v2 * b2f(fq2.w) + v3 * b2f(fq3.w);
  }
  for (; e + 4 <= s1; e += 4) {
    int p0 = colpk[e + 0].x, p1 = colpk[e + 1].x, p2 = colpk[e + 2].x, p3 = colpk[e + 3].x;
    float u0 = exh[e + 0], u1 = exh[e + 1], u2 = exh[e + 2], u3 = exh[e + 3];
    u16x4 fp0 = *reinterpret_cast<const u16x4*>(&feat[(size_t)p0 * 256 + lane * 4]);
    u16x4 fp1 = *reinterpret_cast<const u16x4*>(&feat[(size_t)p1 * 256 + lane * 4]);
    u16x4 fp2 = *reinterpret_cast<const u16x4*>(&feat[(size_t)p2 * 256 + lane * 4]);
    u16x4 fp3 = *reinterpret_cast<const u16x4*>(&feat[(size_t)p3 * 256 + lane * 4]);
    den += (u0 + u1) + (u2 + u3);
    ax += u0 * b2f(fp0.x) + u1 * b2f(fp1.x) + u2 * b2f(fp2.x) + u3 * b2f(fp3.x);
    ay += u0 * b2f(fp0.y) + u1 * b2f(fp1.y) + u2 * b2f(fp2.y) + u3 * b2f(fp3.y);
    az += u0 * b2f(fp0.z) + u1 * b2f(fp1.z) + u2 * b2f(fp2.z) + u3 * b2f(fp3.z);
    aw += u0 * b2f(fp0.w) + u1 * b2f(fp1.w) + u2 * b2f(fp2.w) + u3 * b2f(fp3.w);
  }
  for (; e < s1; ++e) {
    int s = colpk[e].x;
    float xv = exh[e];
    den += xv;
    u16x4 f = *reinterpret_cast<const u16x4*>(&feat[(size_t)s * 256 + lane * 4]);
    ax += xv * b2f(f.x); ay += xv * b2f(f.y); az += xv * b2f(f.z); aw += xv * b2f(f.w);
  }
  float inv = 1.f / den;  // self-loop guarantees den > 0
  ax *= inv; ay *= inv; az *= inv; aw *= inv;

  if (MODE == 0) {
    float4 b4 = *reinterpret_cast<const float4*>(&bias[lane * 4]);
    float vx = ax + b4.x, vy = ay + b4.y, vz = az + b4.z, vw = aw + b4.w;
    float s = vx + vy + vz + vw;
#pragma unroll
    for (int off = 1; off < 64; off <<= 1) s += __shfl_xor(s, off);
    float mu = s * (1.f / 256.f);
    float dx = vx - mu, dy = vy - mu, dz = vz - mu, dw = vw - mu;
    float q = dx * dx + dy * dy + dz * dz + dw * dw;
#pragma unroll
    for (int off = 1; off < 64; off <<= 1) q += __shfl_xor(q, off);
    float inv2 = rsqrtf(q * (1.f / 256.f) + 1e-5f);
    float4 gg = *reinterpret_cast<const float4*>(&g[lane * 4]);
    float4 bb = *reinterpret_cast<const float4*>(&be[lane * 4]);
    u16x4 o;
    o.x = f2b(elu_f(dx * inv2 * gg.x + bb.x));
    o.y = f2b(elu_f(dy * inv2 * gg.y + bb.y));
    o.z = f2b(elu_f(dz * inv2 * gg.z + bb.z));
    o.w = f2b(elu_f(dw * inv2 * gg.w + bb.w));
    u16* rowb = (u16*)out + (size_t)node * 256;
    *reinterpret_cast<u16x4*>(&rowb[lane * 4]) = o;
  } else {
    ax += __shfl_xor(ax, 16); ax += __shfl_xor(ax, 32);
    ay += __shfl_xor(ay, 16); ay += __shfl_xor(ay, 32);
    az += __shfl_xor(az, 16); az += __shfl_xor(az, 32);
    aw += __shfl_xor(aw, 16); aw += __shfl_xor(aw, 32);
    int qd = lane & 15;
    float4 b4 = *reinterpret_cast<const float4*>(&bias[qd * 4]);
    float vx = 0.25f * ax + b4.x, vy = 0.25f * ay + b4.y;
    float vz = 0.25f * az + b4.z, vw = 0.25f * aw + b4.w;
    float s = vx + vy + vz + vw;
#pragma unroll
    for (int off = 1; off < 64; off <<= 1) s += __shfl_xor(s, off);
    float mu = s * (1.f / 256.f);
    float dx = vx - mu, dy = vy - mu, dz = vz - mu, dw = vw - mu;
    float q = dx * dx + dy * dy + dz * dz + dw * dw;
#pragma unroll
    for (int off = 1; off < 64; off <<= 1) q += __shfl_xor(q, off);
    float inv2 = rsqrtf(q * (1.f / 256.f) + 1e-5f);
    if (lane < 16) {
      float4 gg = *reinterpret_cast<const float4*>(&g[qd * 4]);
      float4 bb = *reinterpret_cast<const float4*>(&be[qd * 4]);
      float4 o;
      o.x = elu_f(dx * inv2 * gg.x + bb.x);
      o.y = elu_f(dy * inv2 * gg.y + bb.y);
      o.z = elu_f(dz * inv2 * gg.z + bb.z);
      o.w = elu_f(dw * inv2 * gg.w + bb.w);
      *reinterpret_cast<float4*>(&((float*)out)[(size_t)node * 64 + qd * 4]) = o;
    }
  }
}

// ---------------- value head: out[n,4] ----------------
__global__ __launch_bounds__(256) void value_head_k(const float* __restrict__ hh,
                                                    const float* __restrict__ vw1,
                                                    const float* __restrict__ vb1,
                                                    const float* __restrict__ vw2,
                                                    const float* __restrict__ vb2,
                                                    float* __restrict__ out, int n) {
  __shared__ float w1s[32 * 65];
  __shared__ float hs[4][64];
  __shared__ float vs[4][33];
  int tid = threadIdx.x;
  for (int i = tid; i < 2048; i += 256) w1s[(i >> 6) * 65 + (i & 63)] = vw1[i];
  int wave = tid >> 6, lane = tid & 63;
  int node = blockIdx.x * 4 + wave;
  int nc = node < n ? node : n - 1;
  hs[wave][lane] = hh[(size_t)nc * 64 + lane];
  __syncthreads();
  int j = lane & 31, half = lane >> 5;
  float p = 0.f;
#pragma unroll
  for (int c = 0; c < 32; ++c) p += hs[wave][half * 32 + c] * w1s[j * 65 + half * 32 + c];
  p += __shfl_xor(p, 32);
  float v = elu_f(p + vb1[j]);
  if (half == 0) vs[wave][j] = v;
  __syncthreads();
  if (lane < 4 && node < n) {
    float o = vb2[lane];
#pragma unroll
    for (int jj = 0; jj < 32; ++jj) o += vs[wave][jj] * vw2[lane * 32 + jj];
    out[(size_t)node * 4 + lane] = o;
  }
}

extern "C" void kernel_launch(void* const* d_in, const int* in_sizes, int n_in,
                              void* d_out, int out_size, void* d_ws, size_t ws_size,
                              hipStream_t stream) {
  const float* x      = (const float*)d_in[0];
  const int*   esrc   = (const int*)d_in[1];
  const int*   edst   = (const int*)d_in[2];
  const float* proj_w = (const float*)d_in[3];
  const float* proj_b = (const float*)d_in[4];
  const float* w[3]   = {(const float*)d_in[5],  (const float*)d_in[11], (const float*)d_in[17]};
  const float* a_s[3] = {(const float*)d_in[6],  (const float*)d_in[12], (const float*)d_in[18]};
  const float* a_d[3] = {(const float*)d_in[7],  (const float*)d_in[13], (const float*)d_in[19]};
  const float* bb[3]  = {(const float*)d_in[8],  (const float*)d_in[14], (const float*)d_in[20]};
  const float* gg[3]  = {(const float*)d_in[9],  (const float*)d_in[15], (const float*)d_in[21]};
  const float* be[3]  = {(const float*)d_in[10], (const float*)d_in[16], (const float*)d_in[22]};
  const float* vw1 = (const float*)d_in[23];
  const float* vb1 = (const float*)d_in[24];
  const float* vw2 = (const float*)d_in[25];
  const float* vb2 = (const float*)d_in[26];
  float* outp = (float*)d_out;

  const int n = in_sizes[0] / 128;
  const int E = in_sizes[1];
  const int EE = E + n;
  const int eep = (EE + 255) & ~255;
  const int nbl = (n + 255) / 256;

  // ---- workspace layout ----
  char* p = (char*)d_ws;
  auto alloc = [&](size_t bytes) { char* r = p; p += (bytes + 255) & ~(size_t)255; return r; };
  u16*   hA    = (u16*)alloc((size_t)n * 512);     // packed bf16 [n,256]; hfinal f32 [n,64] later
  u16*   featB = (u16*)alloc((size_t)n * 512);     // bf16 [n,256] gemm output
  float* exT   = (float*)alloc((size_t)eep * 16);  // transposed numerators [4][eep]
  float* asrcN = (float*)alloc((size_t)n * 16);
  float* adstN = (float*)alloc((size_t)n * 16);
  u16* wbp = (u16*)alloc(64 * 128 * 2);
  u16* wb[3];
  wb[0] = (u16*)alloc(256 * 64 * 2);
  wb[1] = (u16*)alloc(256 * 256 * 2);
  wb[2] = (u16*)alloc(256 * 256 * 2);
  int* deg    = (int*)alloc((size_t)n * 4);
  int* rowptr = (int*)alloc((size_t)(n + 1) * 4);
  int* rank   = (int*)alloc((size_t)EE * 4);
  int2* colpk = (int2*)alloc((size_t)EE * 8);
  int* bsum   = (int*)alloc((size_t)nbl * 4);
  float* hfinal = (float*)hA;  // f32 [n,64]; hA dead after layer-2 gemm reads it

  // ---- CSR build + weight conversions ----
  hipMemsetAsync(deg, 0, (size_t)n * sizeof(int), stream);
  cvtdeg_k<<<(155648 + EE + 255) / 256, 256, 0, stream>>>(
      proj_w, w[0], w[1], w[2], wbp, wb[0], wb[1], wb[2], edst, E, EE, deg, rank);
  block_sum_k<<<nbl, 256, 0, stream>>>(deg, bsum, n);
  scan_bsum_k<<<1, 1024, 0, stream>>>(bsum, nbl);
  block_scan_k<<<nbl, 256, 0, stream>>>(deg, bsum, rowptr, n);
  scatterf_k<<<(EE + 1023) / 1024, 256, 0, stream>>>(esrc, edst, rank, rowptr, E, EE, colpk);

  const int nb4 = (n + 3) / 4;
  const int nbg = (n + 127) / 128;
  dim3 blk(256);

  const int Kin[3] = {64, 256, 256};
  for (int i = 0; i < 3; ++i) {
    if (i == 0) {
      // fused proj + layer-0 GEMM: reads f32 x directly (converts while staging)
      gemm2_k<1><<<nbg, 512, 0, stream>>>(nullptr, 0, x, wb[0], wbp, proj_b, featB,
                                          n, 64, a_s[0], a_d[0], asrcN, adstN);
    } else {
      gemm2_k<0><<<nbg, 512, 0, stream>>>(hA, 256, nullptr, wb[i], nullptr, nullptr, featB,
                                          n, Kin[i], a_s[i], a_d[i], asrcN, adstN);
    }
    edge_ex2_k<<<(EE + 255) / 256, 256, 0, stream>>>(colpk, asrcN, adstN, exT, eep, EE);
    if (i < 2) {
      gat_agg4_k<0><<<nb4, blk, 0, stream>>>(featB, exT, eep, rowptr, colpk, bb[i], gg[i], be[i],
                                             (void*)hA, n);
    } else {
      gat_agg4_k<1><<<nb4, blk, 0, stream>>>(featB, exT, eep, rowptr, colpk, bb[i], gg[i], be[i],
                                             (void*)hfinal, n);
    }
  }

  // ---- value head ----
  value_head_k<<<nb4, blk, 0, stream>>>(hfinal, vw1, vb1, vw2, vb2, outp, n);
}